// Round 2
// baseline (8697.716 us; speedup 1.0000x reference)
//
#include <hip/hip_runtime.h>
#include <math.h>

#define HW 16384   // 128*128

__device__ __forceinline__ float gelu_tanh(float x) {
    float x3 = x * x * x;
    float t = tanhf(0.7978845608028654f * (x + 0.044715f * x3));
    return 0.5f * x * (1.0f + t);
}

// ---------------- front: grid + quad + fc0 lift -> xbuf (NB,64,128,128) ----------
__global__ __launch_bounds__(256) void front_kernel(
    const float* __restrict__ x,          // (NB,10,128,128) chunk base
    const float* __restrict__ qa, const float* __restrict__ qb,   // (4,12)
    const float* __restrict__ w1, const float* __restrict__ b1,   // (128,16),(128)
    const float* __restrict__ w2, const float* __restrict__ b2,   // (48,128),(48)
    float* __restrict__ out)              // (NB,64,128,128)
{
    __shared__ float lw1[128 * 16];
    __shared__ float lw2[48 * 128];
    __shared__ float lqa[48], lqb[48], lb1[128], lb2s[48];
    int t = threadIdx.x;
    for (int i = t; i < 128 * 16; i += 256) lw1[i] = w1[i];
    for (int i = t; i < 48 * 128; i += 256) lw2[i] = w2[i];
    if (t < 48) { lqa[t] = qa[t]; lqb[t] = qb[t]; lb2s[t] = b2[t]; }
    if (t < 128) lb1[t] = b1[t];
    __syncthreads();

    int gid = blockIdx.x * 256 + t;       // b*16384 + y*128 + x (b chunk-local)
    int b = gid >> 14;
    int p = gid & 16383;
    int y = p >> 7, xx = p & 127;

    float v[16];
    const float* xb = x + (size_t)b * 10 * HW + p;
#pragma unroll
    for (int c = 0; c < 10; ++c) v[c] = xb[c * HW];
    v[10] = (float)y * (1.0f / 127.0f);
    v[11] = (float)xx * (1.0f / 127.0f);
#pragma unroll
    for (int o = 0; o < 4; ++o) {
        float sa = 0.f, sb = 0.f;
#pragma unroll
        for (int c = 0; c < 12; ++c) { sa += lqa[o * 12 + c] * v[c]; sb += lqb[o * 12 + c] * v[c]; }
        v[12 + o] = sa * sb;
    }
    float lift[48];
#pragma unroll
    for (int o = 0; o < 48; ++o) lift[o] = lb2s[o];
    for (int m = 0; m < 128; ++m) {
        float s = lb1[m];
#pragma unroll
        for (int c = 0; c < 16; ++c) s += lw1[m * 16 + c] * v[c];
        s = gelu_tanh(s);
#pragma unroll
        for (int o = 0; o < 48; ++o) lift[o] += lw2[o * 128 + m] * s;
    }
    float* ob = out + (size_t)b * 64 * HW + p;
#pragma unroll
    for (int c = 0; c < 16; ++c) ob[c * HW] = v[c];
#pragma unroll
    for (int o = 0; o < 48; ++o) ob[(16 + o) * HW] = lift[o];
}

// ---------------- dft1: over W -> kx (0..19).  out (NB*64,128,20) complex --------
__global__ __launch_bounds__(256) void dft1_kernel(
    const float* __restrict__ xin, float2* __restrict__ fw)
{
    __shared__ float tc[128], ts[128];
    int t = threadIdx.x;
    if (t < 128) { float s, c; sincosf(6.283185307179586f * (float)t / 128.0f, &s, &c); tc[t] = c; ts[t] = s; }
    __syncthreads();
    int idx = blockIdx.x * 256 + t;       // (bc*128 + y)*20 + kx
    int kx = idx % 20;
    int ry = idx / 20;
    const float* row = xin + (size_t)ry * 128;
    float re = 0.f, im = 0.f;
#pragma unroll 4
    for (int xx = 0; xx < 128; ++xx) {
        float v = row[xx];
        int tt = (kx * xx) & 127;
        re += v * tc[tt];
        im -= v * ts[tt];
    }
    fw[idx] = make_float2(re, im);
}

// ---------------- dft2: over H -> ky idx 0..39 (0..19, 108..127) ----------------
__global__ __launch_bounds__(256) void dft2_kernel(
    const float2* __restrict__ fw, float2* __restrict__ fm)
{
    __shared__ float tc[128], ts[128];
    int t = threadIdx.x;
    if (t < 128) { float s, c; sincosf(6.283185307179586f * (float)t / 128.0f, &s, &c); tc[t] = c; ts[t] = s; }
    __syncthreads();
    int idx = blockIdx.x * 256 + t;       // (bc*40 + kyi)*20 + kx
    int kx = idx % 20;
    int r = idx / 20;
    int kyi = r % 40;
    int bc = r / 40;
    int ky = kyi + ((kyi >= 20) ? 88 : 0);
    const float2* col = fw + (size_t)bc * 128 * 20 + kx;
    float re = 0.f, im = 0.f;
    for (int y = 0; y < 128; ++y) {
        float2 a = col[(size_t)y * 20];
        int tt = (ky * y) & 127;
        float c = tc[tt], s = ts[tt];
        re += a.x * c + a.y * s;
        im += a.y * c - a.x * s;
    }
    fm[idx] = make_float2(re, im);
}

// ---------------- per-mode 64x64 complex multiply --------------------------------
__global__ __launch_bounds__(256) void specmul_kernel(
    const float2* __restrict__ fm,
    const float* __restrict__ w1r, const float* __restrict__ w1i,
    const float* __restrict__ w2r, const float* __restrict__ w2i,
    float2* __restrict__ fm2, int nb64)
{
    __shared__ float2 lx[32 * 64];   // 16KB (max chunk 32)
    __shared__ float2 lw[64 * 64];   // 32KB
    int t = threadIdx.x;
    int mode = blockIdx.x;           // 0..799
    int region = mode / 400;
    int km = mode % 400;             // kyj*20 + kx
    int kyi = region * 20 + (km / 20);
    int kx = km % 20;
    const float* wr = region ? w2r : w1r;
    const float* wi = region ? w2i : w1i;
    int modeoff = kyi * 20 + kx;
    for (int n = t; n < nb64; n += 256)   // n = b*64 + i
        lx[n] = fm[(size_t)n * 800 + modeoff];
    for (int n = t; n < 4096; n += 256) { // n = i*64 + o
        size_t a = (size_t)n * 400 + km;
        lw[n] = make_float2(wr[a], wi[a]);
    }
    __syncthreads();
    for (int n = t; n < nb64; n += 256) { // n = b*64 + o
        int b = n >> 6, o = n & 63;
        float re = 0.f, im = 0.f;
        const float2* xb = lx + b * 64;
#pragma unroll 8
        for (int i = 0; i < 64; ++i) {
            float2 a = xb[i];
            float2 w = lw[i * 64 + o];
            re += a.x * w.x - a.y * w.y;
            im += a.x * w.y + a.y * w.x;
        }
        fm2[(size_t)n * 800 + modeoff] = make_float2(re, im);
    }
}

// ---------------- inverse over H: ky (40) -> y (128) ------------------------------
__global__ __launch_bounds__(256) void invA_kernel(
    const float2* __restrict__ fm2, float2* __restrict__ fw)
{
    __shared__ float tc[128], ts[128];
    int t = threadIdx.x;
    if (t < 128) { float s, c; sincosf(6.283185307179586f * (float)t / 128.0f, &s, &c); tc[t] = c; ts[t] = s; }
    __syncthreads();
    int idx = blockIdx.x * 256 + t;       // (bc*128 + y)*20 + kx
    int kx = idx % 20;
    int r = idx / 20;
    int y = r & 127;
    int bc = r >> 7;
    const float2* in = fm2 + (size_t)bc * 800 + kx;
    float re = 0.f, im = 0.f;
#pragma unroll 8
    for (int kyi = 0; kyi < 40; ++kyi) {
        int ky = kyi + ((kyi >= 20) ? 88 : 0);
        float2 a = in[(size_t)kyi * 20];
        int tt = (ky * y) & 127;
        float c = tc[tt], s = ts[tt];
        re += a.x * c - a.y * s;
        im += a.x * s + a.y * c;
    }
    fw[idx] = make_float2(re, im);
}

// ---------------- inverse rfft over W: kx (20) -> x (128), real ------------------
__global__ __launch_bounds__(256) void invB_kernel(
    const float2* __restrict__ fw, float* __restrict__ sbuf)
{
    __shared__ float tc[128], ts[128];
    int t = threadIdx.x;
    if (t < 128) { float s, c; sincosf(6.283185307179586f * (float)t / 128.0f, &s, &c); tc[t] = c; ts[t] = s; }
    __syncthreads();
    int idx = blockIdx.x * 256 + t;       // bc*16384 + y*128 + x
    int xx = idx & 127;
    int ry = idx >> 7;                    // bc*128 + y
    const float2* in = fw + (size_t)ry * 20;
    float2 a0 = in[0];
    float acc = 0.5f * a0.x;              // Im(bin 0) dropped (pocketfft c2r semantics)
#pragma unroll
    for (int k = 1; k < 20; ++k) {
        float2 a = in[k];
        int tt = (k * xx) & 127;
        acc += a.x * tc[tt] - a.y * ts[tt];
    }
    sbuf[idx] = acc * (2.0f / 16384.0f);
}

// ---------------- circular conv 3x3, 64->64 channels ------------------------------
__global__ __launch_bounds__(256) void conv3_kernel(
    const float* __restrict__ xin,   // (NB,64,128,128)
    const float* __restrict__ cw,    // (64,64,3,3) layer base
    const float* __restrict__ cb,    // (64)
    float* __restrict__ cbuf)
{
    int t = threadIdx.x;
    int tile = blockIdx.x;           // 0..63 (8x8 tiles of 16x16)
    int og = blockIdx.y;             // 0..15 -> 4 output channels each
    int b  = blockIdx.z;             // chunk-local batch
    int ty = tile >> 3, tx = tile & 7;
    int ly = t >> 4, lx = t & 15;
    int y = ty * 16 + ly, xx = tx * 16 + lx;
    int ym = (y + 127) & 127, yp = (y + 1) & 127;
    int xm = (xx + 127) & 127, xp = (xx + 1) & 127;
    int off[9] = { ym * 128 + xm, ym * 128 + xx, ym * 128 + xp,
                   y  * 128 + xm, y  * 128 + xx, y  * 128 + xp,
                   yp * 128 + xm, yp * 128 + xx, yp * 128 + xp };
    int o0 = og * 4;
    float acc0 = cb[o0], acc1 = cb[o0 + 1], acc2 = cb[o0 + 2], acc3 = cb[o0 + 3];
    const float* xb = xin + (size_t)b * 64 * HW;
    const float* w0 = cw + (size_t)o0 * 576;
    for (int i = 0; i < 64; ++i) {
        const float* xi = xb + (size_t)i * HW;
        const float* wi = w0 + i * 9;
#pragma unroll
        for (int k = 0; k < 9; ++k) {
            float v = xi[off[k]];
            acc0 += wi[k]        * v;
            acc1 += wi[576 + k]  * v;
            acc2 += wi[1152 + k] * v;
            acc3 += wi[1728 + k] * v;
        }
    }
    float* ob = cbuf + (size_t)b * 64 * HW + (size_t)o0 * HW + (size_t)y * 128 + xx;
    ob[0] = acc0; ob[HW] = acc1; ob[2 * HW] = acc2; ob[3 * HW] = acc3;
}

// ---------------- pointwise: [x1;x2;prods] -> pw -> tanh -> residual -------------
__global__ __launch_bounds__(256) void combine_kernel(
    const float* __restrict__ s1,    // spectral out
    const float* __restrict__ c2,    // conv out
    const float* __restrict__ pw,    // (64,130) layer base
    const float* __restrict__ pb,    // (64)
    float* __restrict__ xio)         // running x (read-modify-write)
{
    __shared__ float lw[64 * 130];
    __shared__ float lpb[64];
    int t = threadIdx.x;
    for (int n = t; n < 64 * 130; n += 256) lw[n] = pw[n];
    if (t < 64) lpb[t] = pb[t];
    __syncthreads();
    int gid = blockIdx.x * 256 + t;
    int b = gid >> 14, p = gid & 16383;
    const float* s1b = s1 + (size_t)b * 64 * HW + p;
    const float* c2b = c2 + (size_t)b * 64 * HW + p;
    float acc[64];
#pragma unroll
    for (int o = 0; o < 64; ++o) acc[o] = lpb[o];
    float q0 = 0.f, q1 = 0.f, q2 = 0.f, q3 = 0.f;
    for (int c = 0; c < 64; ++c) {
        float v = s1b[(size_t)c * HW];
        if (c == 0) q0 = v;
        if (c == 1) q1 = v;
        if (c == 2) q2 = v;
        if (c == 3) q3 = v;
#pragma unroll
        for (int o = 0; o < 64; ++o) acc[o] += lw[o * 130 + c] * v;
    }
    for (int c = 0; c < 64; ++c) {
        float v = c2b[(size_t)c * HW];
#pragma unroll
        for (int o = 0; o < 64; ++o) acc[o] += lw[o * 130 + 64 + c] * v;
    }
    float p0 = q0 * q2, p1 = q1 * q3;
#pragma unroll
    for (int o = 0; o < 64; ++o) acc[o] += lw[o * 130 + 128] * p0 + lw[o * 130 + 129] * p1;
    float* xb = xio + (size_t)b * 64 * HW + p;
#pragma unroll
    for (int o = 0; o < 64; ++o) xb[(size_t)o * HW] += tanhf(acc[o]);
}

// ---------------- fc1 head: 64 -> gelu(128) -> 1 ---------------------------------
__global__ __launch_bounds__(256) void fc1_kernel(
    const float* __restrict__ xin,
    const float* __restrict__ w1, const float* __restrict__ b1,   // (128,64),(128)
    const float* __restrict__ w2, const float* __restrict__ b2,   // (1,128),(1)
    float* __restrict__ out)
{
    __shared__ float lw1[128 * 64];
    __shared__ float lb1[128], lw2[128];
    int t = threadIdx.x;
    for (int n = t; n < 128 * 64; n += 256) lw1[n] = w1[n];
    if (t < 128) { lb1[t] = b1[t]; lw2[t] = w2[t]; }
    __syncthreads();
    int gid = blockIdx.x * 256 + t;
    int b = gid >> 14, p = gid & 16383;
    const float* xb = xin + (size_t)b * 64 * HW + p;
    float v[64];
#pragma unroll
    for (int c = 0; c < 64; ++c) v[c] = xb[(size_t)c * HW];
    float o = b2[0];
    for (int m = 0; m < 128; ++m) {
        float s = lb1[m];
#pragma unroll
        for (int c = 0; c < 64; ++c) s += lw1[m * 64 + c] * v[c];
        o += lw2[m] * gelu_tanh(s);
    }
    out[gid] = o;
}

extern "C" void kernel_launch(void* const* d_in, const int* in_sizes, int n_in,
                              void* d_out, int out_size, void* d_ws, size_t ws_size,
                              hipStream_t stream) {
    const float* x      = (const float*)d_in[0];
    const float* qa     = (const float*)d_in[1];
    const float* qb     = (const float*)d_in[2];
    const float* fc0w1  = (const float*)d_in[3];
    const float* fc0b1  = (const float*)d_in[4];
    const float* fc0w2  = (const float*)d_in[5];
    const float* fc0b2  = (const float*)d_in[6];
    const float* sw1r   = (const float*)d_in[7];
    const float* sw1i   = (const float*)d_in[8];
    const float* sw2r   = (const float*)d_in[9];
    const float* sw2i   = (const float*)d_in[10];
    const float* cw     = (const float*)d_in[11];
    const float* cb     = (const float*)d_in[12];
    const float* pw     = (const float*)d_in[13];
    const float* pb     = (const float*)d_in[14];
    const float* fc1w1  = (const float*)d_in[15];
    const float* fc1b1  = (const float*)d_in[16];
    const float* fc1w2  = (const float*)d_in[17];
    const float* fc1b2  = (const float*)d_in[18];

    // --- adaptive batch chunking: per-batch float footprint ---
    // xbuf + sbuf + cbuf = 3*1048576, fw = 327680, fm+fm2 = 2*102400
    const size_t PER_B_FLOATS = 3u * 1048576u + 327680u + 2u * 102400u; // 3,678,208
    int NB = 32;
    while (NB > 1 && (size_t)NB * PER_B_FLOATS * 4 > ws_size) NB >>= 1;
    if ((size_t)NB * PER_B_FLOATS * 4 > ws_size) return;  // can't run at all

    const size_t ACT = (size_t)NB * 1048576u;   // NB*64*128*128
    float*  xbuf = (float*)d_ws;
    float*  sbuf = xbuf + ACT;
    float*  cbuf = sbuf + ACT;
    float2* fw   = (float2*)(cbuf + ACT);       // NB*64*128*20 complex
    float2* fm   = fw + (size_t)NB * 163840u;   // NB*64*40*20 complex
    float2* fm2  = fm + (size_t)NB * 51200u;

    for (int b0 = 0; b0 < 32; b0 += NB) {
        front_kernel<<<NB * 64, 256, 0, stream>>>(
            x + (size_t)b0 * 10 * HW, qa, qb, fc0w1, fc0b1, fc0w2, fc0b2, xbuf);

        for (int L = 0; L < 4; ++L) {
            const size_t swoff = (size_t)L * 1638400;   // 64*64*20*20
            dft1_kernel<<<NB * 640, 256, 0, stream>>>(xbuf, fw);
            dft2_kernel<<<NB * 200, 256, 0, stream>>>(fw, fm);
            specmul_kernel<<<800, 256, 0, stream>>>(fm, sw1r + swoff, sw1i + swoff,
                                                    sw2r + swoff, sw2i + swoff, fm2, NB * 64);
            invA_kernel<<<NB * 640, 256, 0, stream>>>(fm2, fw);
            invB_kernel<<<NB * 4096, 256, 0, stream>>>(fw, sbuf);
            conv3_kernel<<<dim3(64, 16, NB), 256, 0, stream>>>(
                xbuf, cw + (size_t)L * 36864, cb + (size_t)L * 64, cbuf);
            combine_kernel<<<NB * 64, 256, 0, stream>>>(
                sbuf, cbuf, pw + (size_t)L * 8320, pb + (size_t)L * 64, xbuf);
        }

        fc1_kernel<<<NB * 64, 256, 0, stream>>>(
            xbuf, fc1w1, fc1b1, fc1w2, fc1b2, (float*)d_out + (size_t)b0 * HW);
    }
}

// Round 3
// 4897.425 us; speedup vs baseline: 1.7760x; 1.7760x over previous
//
#include <hip/hip_runtime.h>
#include <math.h>

#define HW 16384   // 128*128

typedef __attribute__((ext_vector_type(8))) short short8;
typedef __attribute__((ext_vector_type(4))) float f32x4;

__device__ __forceinline__ float gelu_tanh(float x) {
    float x3 = x * x * x;
    float t = tanhf(0.7978845608028654f * (x + 0.044715f * x3));
    return 0.5f * x * (1.0f + t);
}

__device__ __forceinline__ unsigned f2bf(float f) {
    unsigned u = __builtin_bit_cast(unsigned, f);
    return (u + 0x7FFFu + ((u >> 16) & 1u)) >> 16;   // RNE bf16
}

// ---------------- front: grid + quad + fc0 lift -> xbuf (NB,64,128,128) ----------
__global__ __launch_bounds__(256) void front_kernel(
    const float* __restrict__ x,          // (NB,10,128,128) chunk base
    const float* __restrict__ qa, const float* __restrict__ qb,   // (4,12)
    const float* __restrict__ w1, const float* __restrict__ b1,   // (128,16),(128)
    const float* __restrict__ w2, const float* __restrict__ b2,   // (48,128),(48)
    float* __restrict__ out)              // (NB,64,128,128)
{
    __shared__ float lw1[128 * 16];
    __shared__ float lw2[48 * 128];
    __shared__ float lqa[48], lqb[48], lb1[128], lb2s[48];
    int t = threadIdx.x;
    for (int i = t; i < 128 * 16; i += 256) lw1[i] = w1[i];
    for (int i = t; i < 48 * 128; i += 256) lw2[i] = w2[i];
    if (t < 48) { lqa[t] = qa[t]; lqb[t] = qb[t]; lb2s[t] = b2[t]; }
    if (t < 128) lb1[t] = b1[t];
    __syncthreads();

    int gid = blockIdx.x * 256 + t;       // b*16384 + y*128 + x (b chunk-local)
    int b = gid >> 14;
    int p = gid & 16383;
    int y = p >> 7, xx = p & 127;

    float v[16];
    const float* xb = x + (size_t)b * 10 * HW + p;
#pragma unroll
    for (int c = 0; c < 10; ++c) v[c] = xb[c * HW];
    v[10] = (float)y * (1.0f / 127.0f);
    v[11] = (float)xx * (1.0f / 127.0f);
#pragma unroll
    for (int o = 0; o < 4; ++o) {
        float sa = 0.f, sb = 0.f;
#pragma unroll
        for (int c = 0; c < 12; ++c) { sa += lqa[o * 12 + c] * v[c]; sb += lqb[o * 12 + c] * v[c]; }
        v[12 + o] = sa * sb;
    }
    float lift[48];
#pragma unroll
    for (int o = 0; o < 48; ++o) lift[o] = lb2s[o];
    for (int m = 0; m < 128; ++m) {
        float s = lb1[m];
#pragma unroll
        for (int c = 0; c < 16; ++c) s += lw1[m * 16 + c] * v[c];
        s = gelu_tanh(s);
#pragma unroll
        for (int o = 0; o < 48; ++o) lift[o] += lw2[o * 128 + m] * s;
    }
    float* ob = out + (size_t)b * 64 * HW + p;
#pragma unroll
    for (int c = 0; c < 16; ++c) ob[c * HW] = v[c];
#pragma unroll
    for (int o = 0; o < 48; ++o) ob[(16 + o) * HW] = lift[o];
}

// ---------------- dft1: over W -> kx (0..19).  out (NB*64,128,20) complex --------
__global__ __launch_bounds__(256) void dft1_kernel(
    const float* __restrict__ xin, float2* __restrict__ fw)
{
    __shared__ float tc[128], ts[128];
    int t = threadIdx.x;
    if (t < 128) { float s, c; sincosf(6.283185307179586f * (float)t / 128.0f, &s, &c); tc[t] = c; ts[t] = s; }
    __syncthreads();
    int idx = blockIdx.x * 256 + t;       // (bc*128 + y)*20 + kx
    int kx = idx % 20;
    int ry = idx / 20;
    const float* row = xin + (size_t)ry * 128;
    float re = 0.f, im = 0.f;
#pragma unroll 4
    for (int xx = 0; xx < 128; ++xx) {
        float v = row[xx];
        int tt = (kx * xx) & 127;
        re += v * tc[tt];
        im -= v * ts[tt];
    }
    fw[idx] = make_float2(re, im);
}

// ---------------- dft2: over H -> ky idx 0..39 (0..19, 108..127) ----------------
__global__ __launch_bounds__(256) void dft2_kernel(
    const float2* __restrict__ fw, float2* __restrict__ fm)
{
    __shared__ float tc[128], ts[128];
    int t = threadIdx.x;
    if (t < 128) { float s, c; sincosf(6.283185307179586f * (float)t / 128.0f, &s, &c); tc[t] = c; ts[t] = s; }
    __syncthreads();
    int idx = blockIdx.x * 256 + t;       // (bc*40 + kyi)*20 + kx
    int kx = idx % 20;
    int r = idx / 20;
    int kyi = r % 40;
    int bc = r / 40;
    int ky = kyi + ((kyi >= 20) ? 88 : 0);
    const float2* col = fw + (size_t)bc * 128 * 20 + kx;
    float re = 0.f, im = 0.f;
    for (int y = 0; y < 128; ++y) {
        float2 a = col[(size_t)y * 20];
        int tt = (ky * y) & 127;
        float c = tc[tt], s = ts[tt];
        re += a.x * c + a.y * s;
        im += a.y * c - a.x * s;
    }
    fm[idx] = make_float2(re, im);
}

// ---------------- per-mode 64x64 complex multiply --------------------------------
__global__ __launch_bounds__(256) void specmul_kernel(
    const float2* __restrict__ fm,
    const float* __restrict__ w1r, const float* __restrict__ w1i,
    const float* __restrict__ w2r, const float* __restrict__ w2i,
    float2* __restrict__ fm2, int nb64)
{
    __shared__ float2 lx[32 * 64];   // 16KB (max chunk 32)
    __shared__ float2 lw[64 * 64];   // 32KB
    int t = threadIdx.x;
    int mode = blockIdx.x;           // 0..799
    int region = mode / 400;
    int km = mode % 400;             // kyj*20 + kx
    int kyi = region * 20 + (km / 20);
    int kx = km % 20;
    const float* wr = region ? w2r : w1r;
    const float* wi = region ? w2i : w1i;
    int modeoff = kyi * 20 + kx;
    for (int n = t; n < nb64; n += 256)   // n = b*64 + i
        lx[n] = fm[(size_t)n * 800 + modeoff];
    for (int n = t; n < 4096; n += 256) { // n = i*64 + o
        size_t a = (size_t)n * 400 + km;
        lw[n] = make_float2(wr[a], wi[a]);
    }
    __syncthreads();
    for (int n = t; n < nb64; n += 256) { // n = b*64 + o
        int b = n >> 6, o = n & 63;
        float re = 0.f, im = 0.f;
        const float2* xb = lx + b * 64;
#pragma unroll 8
        for (int i = 0; i < 64; ++i) {
            float2 a = xb[i];
            float2 w = lw[i * 64 + o];
            re += a.x * w.x - a.y * w.y;
            im += a.x * w.y + a.y * w.x;
        }
        fm2[(size_t)n * 800 + modeoff] = make_float2(re, im);
    }
}

// ---------------- inverse over H: ky (40) -> y (128) ------------------------------
__global__ __launch_bounds__(256) void invA_kernel(
    const float2* __restrict__ fm2, float2* __restrict__ fw)
{
    __shared__ float tc[128], ts[128];
    int t = threadIdx.x;
    if (t < 128) { float s, c; sincosf(6.283185307179586f * (float)t / 128.0f, &s, &c); tc[t] = c; ts[t] = s; }
    __syncthreads();
    int idx = blockIdx.x * 256 + t;       // (bc*128 + y)*20 + kx
    int kx = idx % 20;
    int r = idx / 20;
    int y = r & 127;
    int bc = r >> 7;
    const float2* in = fm2 + (size_t)bc * 800 + kx;
    float re = 0.f, im = 0.f;
#pragma unroll 8
    for (int kyi = 0; kyi < 40; ++kyi) {
        int ky = kyi + ((kyi >= 20) ? 88 : 0);
        float2 a = in[(size_t)kyi * 20];
        int tt = (ky * y) & 127;
        float c = tc[tt], s = ts[tt];
        re += a.x * c - a.y * s;
        im += a.x * s + a.y * c;
    }
    fw[idx] = make_float2(re, im);
}

// ---------------- inverse rfft over W: kx (20) -> x (128), real ------------------
__global__ __launch_bounds__(256) void invB_kernel(
    const float2* __restrict__ fw, float* __restrict__ sbuf)
{
    __shared__ float tc[128], ts[128];
    int t = threadIdx.x;
    if (t < 128) { float s, c; sincosf(6.283185307179586f * (float)t / 128.0f, &s, &c); tc[t] = c; ts[t] = s; }
    __syncthreads();
    int idx = blockIdx.x * 256 + t;       // bc*16384 + y*128 + x
    int xx = idx & 127;
    int ry = idx >> 7;                    // bc*128 + y
    const float2* in = fw + (size_t)ry * 20;
    float2 a0 = in[0];
    float acc = 0.5f * a0.x;              // Im(bin 0) dropped (pocketfft c2r semantics)
#pragma unroll
    for (int k = 1; k < 20; ++k) {
        float2 a = in[k];
        int tt = (k * xx) & 127;
        acc += a.x * tc[tt] - a.y * ts[tt];
    }
    sbuf[idx] = acc * (2.0f / 16384.0f);
}

// ---------------- weight repack for MFMA conv: (L,o,i,ky,kx) -> bf16 [L][o][tap*64+i]
__global__ __launch_bounds__(256) void packw_kernel(
    const float* __restrict__ cw, short* __restrict__ wpk)
{
    int idx = blockIdx.x * 256 + threadIdx.x;
    if (idx >= 4 * 64 * 576) return;
    int L = idx / 36864, r = idx % 36864;
    int o = r / 576, k = r % 576;
    int tap = k >> 6, i = k & 63;
    float f = cw[((size_t)(L * 64 + o) * 64 + i) * 9 + tap];
    wpk[idx] = (short)f2bf(f);
}

// ---------------- circular conv 3x3 via bf16 MFMA implicit GEMM -------------------
// block: one (b, y) row. M=64 outs, N=128 x, K=576 (tap*64+i). 4 waves x (M16,N128).
__global__ __launch_bounds__(256) void conv3_mfma_kernel(
    const float* __restrict__ xin,   // (NB,64,128,128)
    const short* __restrict__ wpk,   // (64,576) bf16, layer base
    const float* __restrict__ cb,    // (64)
    float* __restrict__ cbuf)
{
    __shared__ short xlds[3 * 128 * 64];   // 48KB: [row][x][i] with i-group XOR-swizzle
    int t = threadIdx.x;
    int y = blockIdx.x;
    int b = blockIdx.y;
    int lane = t & 63, wid = t >> 6;

    // ---- stage rows y-1,y,y+1 (64ch x 128x) as bf16 pairs ----
    const float* xb = xin + (size_t)b * 64 * HW;
#pragma unroll 4
    for (int p = 0; p < 48; ++p) {        // 12288 i-pairs total
        int linear = p * 256 + t;
        int x  = linear & 127;
        int ip = (linear >> 7) & 31;      // i/2
        int row = linear >> 12;           // 0..2
        int i = ip * 2;
        int yy = (y + row + 127) & 127;
        float f0 = xb[(size_t)i * HW + yy * 128 + x];
        float f1 = xb[(size_t)(i + 1) * HW + yy * 128 + x];
        unsigned h = f2bf(f0) | (f2bf(f1) << 16);
        int g = (i >> 3) ^ (x & 7);
        int off = (row * 128 + x) * 64 + g * 8 + (i & 7);
        *(unsigned*)&xlds[off] = h;
    }

    // ---- A preload: wave's 16x576 weight slice into registers ----
    int o0 = wid * 16;
    const short* wbase = wpk + (size_t)(o0 + (lane & 15)) * 576 + (lane >> 4) * 8;
    short8 aF[18];
#pragma unroll
    for (int s = 0; s < 18; ++s)
        aF[s] = *(const short8*)(wbase + s * 32);

    __syncthreads();

    // ---- MFMA main: k-step s covers tap=s>>1, i in [(s&1)*32, +32) ----
    f32x4 acc[8];
#pragma unroll
    for (int f = 0; f < 8; ++f) acc[f] = (f32x4){0.f, 0.f, 0.f, 0.f};
#pragma unroll
    for (int s = 0; s < 18; ++s) {
        const int tap = s >> 1;
        const int ky = tap / 3, kx = tap % 3;
        int ig = (s & 1) * 4 + (lane >> 4);
#pragma unroll
        for (int f = 0; f < 8; ++f) {
            int xx = (f * 16 + (lane & 15) + kx + 127) & 127;
            int off = (ky * 128 + xx) * 64 + ((ig ^ (xx & 7)) << 3);
            short8 bF = *(const short8*)&xlds[off];
            acc[f] = __builtin_amdgcn_mfma_f32_16x16x32_bf16(aF[s], bF, acc[f], 0, 0, 0);
        }
    }

    // ---- epilogue: D col=lane&15 (n=x), row=(lane>>4)*4+reg (m=o) ----
    int ob = o0 + (lane >> 4) * 4;
    float bias0 = cb[ob], bias1 = cb[ob + 1], bias2 = cb[ob + 2], bias3 = cb[ob + 3];
    float* obase = cbuf + (size_t)b * 64 * HW + (size_t)y * 128;
#pragma unroll
    for (int f = 0; f < 8; ++f) {
        int x = f * 16 + (lane & 15);
        obase[(size_t)(ob    ) * HW + x] = acc[f][0] + bias0;
        obase[(size_t)(ob + 1) * HW + x] = acc[f][1] + bias1;
        obase[(size_t)(ob + 2) * HW + x] = acc[f][2] + bias2;
        obase[(size_t)(ob + 3) * HW + x] = acc[f][3] + bias3;
    }
}

// ---------------- pointwise: [x1;x2;prods] -> pw -> tanh -> residual -------------
__global__ __launch_bounds__(256) void combine_kernel(
    const float* __restrict__ s1,    // spectral out
    const float* __restrict__ c2,    // conv out
    const float* __restrict__ pw,    // (64,130) layer base
    const float* __restrict__ pb,    // (64)
    float* __restrict__ xio)         // running x (read-modify-write)
{
    __shared__ float lw[64 * 130];
    __shared__ float lpb[64];
    int t = threadIdx.x;
    for (int n = t; n < 64 * 130; n += 256) lw[n] = pw[n];
    if (t < 64) lpb[t] = pb[t];
    __syncthreads();
    int gid = blockIdx.x * 256 + t;
    int b = gid >> 14, p = gid & 16383;
    const float* s1b = s1 + (size_t)b * 64 * HW + p;
    const float* c2b = c2 + (size_t)b * 64 * HW + p;
    float acc[64];
#pragma unroll
    for (int o = 0; o < 64; ++o) acc[o] = lpb[o];
    float q0 = 0.f, q1 = 0.f, q2 = 0.f, q3 = 0.f;
    for (int c = 0; c < 64; ++c) {
        float v = s1b[(size_t)c * HW];
        if (c == 0) q0 = v;
        if (c == 1) q1 = v;
        if (c == 2) q2 = v;
        if (c == 3) q3 = v;
#pragma unroll
        for (int o = 0; o < 64; ++o) acc[o] += lw[o * 130 + c] * v;
    }
    for (int c = 0; c < 64; ++c) {
        float v = c2b[(size_t)c * HW];
#pragma unroll
        for (int o = 0; o < 64; ++o) acc[o] += lw[o * 130 + 64 + c] * v;
    }
    float p0 = q0 * q2, p1 = q1 * q3;
#pragma unroll
    for (int o = 0; o < 64; ++o) acc[o] += lw[o * 130 + 128] * p0 + lw[o * 130 + 129] * p1;
    float* xb = xio + (size_t)b * 64 * HW + p;
#pragma unroll
    for (int o = 0; o < 64; ++o) xb[(size_t)o * HW] += tanhf(acc[o]);
}

// ---------------- fc1 head: 64 -> gelu(128) -> 1 ---------------------------------
__global__ __launch_bounds__(256) void fc1_kernel(
    const float* __restrict__ xin,
    const float* __restrict__ w1, const float* __restrict__ b1,   // (128,64),(128)
    const float* __restrict__ w2, const float* __restrict__ b2,   // (1,128),(1)
    float* __restrict__ out)
{
    __shared__ float lw1[128 * 64];
    __shared__ float lb1[128], lw2[128];
    int t = threadIdx.x;
    for (int n = t; n < 128 * 64; n += 256) lw1[n] = w1[n];
    if (t < 128) { lb1[t] = b1[t]; lw2[t] = w2[t]; }
    __syncthreads();
    int gid = blockIdx.x * 256 + t;
    int b = gid >> 14, p = gid & 16383;
    const float* xb = xin + (size_t)b * 64 * HW + p;
    float v[64];
#pragma unroll
    for (int c = 0; c < 64; ++c) v[c] = xb[(size_t)c * HW];
    float o = b2[0];
    for (int m = 0; m < 128; ++m) {
        float s = lb1[m];
#pragma unroll
        for (int c = 0; c < 64; ++c) s += lw1[m * 64 + c] * v[c];
        o += lw2[m] * gelu_tanh(s);
    }
    out[gid] = o;
}

extern "C" void kernel_launch(void* const* d_in, const int* in_sizes, int n_in,
                              void* d_out, int out_size, void* d_ws, size_t ws_size,
                              hipStream_t stream) {
    const float* x      = (const float*)d_in[0];
    const float* qa     = (const float*)d_in[1];
    const float* qb     = (const float*)d_in[2];
    const float* fc0w1  = (const float*)d_in[3];
    const float* fc0b1  = (const float*)d_in[4];
    const float* fc0w2  = (const float*)d_in[5];
    const float* fc0b2  = (const float*)d_in[6];
    const float* sw1r   = (const float*)d_in[7];
    const float* sw1i   = (const float*)d_in[8];
    const float* sw2r   = (const float*)d_in[9];
    const float* sw2i   = (const float*)d_in[10];
    const float* cw     = (const float*)d_in[11];
    const float* cb     = (const float*)d_in[12];
    const float* pw     = (const float*)d_in[13];
    const float* pb     = (const float*)d_in[14];
    const float* fc1w1  = (const float*)d_in[15];
    const float* fc1b1  = (const float*)d_in[16];
    const float* fc1w2  = (const float*)d_in[17];
    const float* fc1b2  = (const float*)d_in[18];

    // --- workspace: packed conv weights (bf16) + adaptive batch chunking ---
    const size_t WPK_SHORTS = 4u * 64u * 576u;               // 147456
    const size_t WPK_FLOATS = (WPK_SHORTS + 1) / 2;          // 73728
    const size_t PER_B_FLOATS = 3u * 1048576u + 327680u + 2u * 102400u; // 3,678,208
    int NB = 32;
    while (NB > 1 && ((size_t)NB * PER_B_FLOATS + WPK_FLOATS) * 4 > ws_size) NB >>= 1;
    if (((size_t)NB * PER_B_FLOATS + WPK_FLOATS) * 4 > ws_size) return;

    short* wpk = (short*)d_ws;
    float* base = (float*)d_ws + WPK_FLOATS;

    const size_t ACT = (size_t)NB * 1048576u;   // NB*64*128*128
    float*  xbuf = base;
    float*  sbuf = xbuf + ACT;
    float*  cbuf = sbuf + ACT;
    float2* fw   = (float2*)(cbuf + ACT);       // NB*64*128*20 complex
    float2* fm   = fw + (size_t)NB * 163840u;   // NB*64*40*20 complex
    float2* fm2  = fm + (size_t)NB * 51200u;

    packw_kernel<<<(int)((WPK_SHORTS + 255) / 256), 256, 0, stream>>>(cw, wpk);

    for (int b0 = 0; b0 < 32; b0 += NB) {
        front_kernel<<<NB * 64, 256, 0, stream>>>(
            x + (size_t)b0 * 10 * HW, qa, qb, fc0w1, fc0b1, fc0w2, fc0b2, xbuf);

        for (int L = 0; L < 4; ++L) {
            const size_t swoff = (size_t)L * 1638400;   // 64*64*20*20
            dft1_kernel<<<NB * 640, 256, 0, stream>>>(xbuf, fw);
            dft2_kernel<<<NB * 200, 256, 0, stream>>>(fw, fm);
            specmul_kernel<<<800, 256, 0, stream>>>(fm, sw1r + swoff, sw1i + swoff,
                                                    sw2r + swoff, sw2i + swoff, fm2, NB * 64);
            invA_kernel<<<NB * 640, 256, 0, stream>>>(fm2, fw);
            invB_kernel<<<NB * 4096, 256, 0, stream>>>(fw, sbuf);
            conv3_mfma_kernel<<<dim3(128, NB), 256, 0, stream>>>(
                xbuf, wpk + (size_t)L * 36864, cb + (size_t)L * 64, cbuf);
            combine_kernel<<<NB * 64, 256, 0, stream>>>(
                sbuf, cbuf, pw + (size_t)L * 8320, pb + (size_t)L * 64, xbuf);
        }

        fc1_kernel<<<NB * 64, 256, 0, stream>>>(
            xbuf, fc1w1, fc1b1, fc1w2, fc1b2, (float*)d_out + (size_t)b0 * HW);
    }
}

// Round 4
// 2764.063 us; speedup vs baseline: 3.1467x; 1.7718x over previous
//
#include <hip/hip_runtime.h>
#include <math.h>

#define HW 16384   // 128*128

typedef __attribute__((ext_vector_type(8))) short short8;
typedef __attribute__((ext_vector_type(4))) float f32x4;
typedef unsigned int u32;

__device__ __forceinline__ float gelu_tanh(float x) {
    float x3 = x * x * x;
    float t = tanhf(0.7978845608028654f * (x + 0.044715f * x3));
    return 0.5f * x * (1.0f + t);
}

__device__ __forceinline__ u32 f2bf(float f) {
    u32 u = __builtin_bit_cast(u32, f);
    return (u + 0x7FFFu + ((u >> 16) & 1u)) >> 16;   // RNE bf16
}
__device__ __forceinline__ u32 pack2(float a, float b) {
    return f2bf(a) | (f2bf(b) << 16);
}
__device__ __forceinline__ float bf2f(u32 h) {
    u32 u = h << 16;
    return __builtin_bit_cast(float, u);
}

// ---------------- front: grid + quad + fc0 lift -> xbuf (NB,64,128,128) ----------
__global__ __launch_bounds__(256) void front_kernel(
    const float* __restrict__ x,
    const float* __restrict__ qa, const float* __restrict__ qb,
    const float* __restrict__ w1, const float* __restrict__ b1,
    const float* __restrict__ w2, const float* __restrict__ b2,
    float* __restrict__ out)
{
    __shared__ float lw1[128 * 16];
    __shared__ float lw2[48 * 128];
    __shared__ float lqa[48], lqb[48], lb1[128], lb2s[48];
    int t = threadIdx.x;
    for (int i = t; i < 128 * 16; i += 256) lw1[i] = w1[i];
    for (int i = t; i < 48 * 128; i += 256) lw2[i] = w2[i];
    if (t < 48) { lqa[t] = qa[t]; lqb[t] = qb[t]; lb2s[t] = b2[t]; }
    if (t < 128) lb1[t] = b1[t];
    __syncthreads();

    int gid = blockIdx.x * 256 + t;
    int b = gid >> 14;
    int p = gid & 16383;
    int y = p >> 7, xx = p & 127;

    float v[16];
    const float* xb = x + (size_t)b * 10 * HW + p;
#pragma unroll
    for (int c = 0; c < 10; ++c) v[c] = xb[c * HW];
    v[10] = (float)y * (1.0f / 127.0f);
    v[11] = (float)xx * (1.0f / 127.0f);
#pragma unroll
    for (int o = 0; o < 4; ++o) {
        float sa = 0.f, sb = 0.f;
#pragma unroll
        for (int c = 0; c < 12; ++c) { sa += lqa[o * 12 + c] * v[c]; sb += lqb[o * 12 + c] * v[c]; }
        v[12 + o] = sa * sb;
    }
    float lift[48];
#pragma unroll
    for (int o = 0; o < 48; ++o) lift[o] = lb2s[o];
    for (int m = 0; m < 128; ++m) {
        float s = lb1[m];
#pragma unroll
        for (int c = 0; c < 16; ++c) s += lw1[m * 16 + c] * v[c];
        s = gelu_tanh(s);
#pragma unroll
        for (int o = 0; o < 48; ++o) lift[o] += lw2[o * 128 + m] * s;
    }
    float* ob = out + (size_t)b * 64 * HW + p;
#pragma unroll
    for (int c = 0; c < 16; ++c) ob[c * HW] = v[c];
#pragma unroll
    for (int o = 0; o < 48; ++o) ob[(16 + o) * HW] = lift[o];
}

// ---------------- const packs ------------------------------------------------------
// conv weights: (L,o,i,ky,kx) -> bf16 [L][o][tap*64+i]
__global__ __launch_bounds__(256) void packw_kernel(
    const float* __restrict__ cw, short* __restrict__ wpk)
{
    int idx = blockIdx.x * 256 + threadIdx.x;
    if (idx >= 4 * 64 * 576) return;
    int L = idx / 36864, r = idx % 36864;
    int o = r / 576, k = r % 576;
    int tap = k >> 6, i = k & 63;
    wpk[idx] = (short)f2bf(cw[((size_t)(L * 64 + o) * 64 + i) * 9 + tap]);
}
// pw first 128 cols: bf16 [L][o][128]
__global__ __launch_bounds__(256) void packpw_kernel(
    const float* __restrict__ pw, short* __restrict__ pwk)
{
    int idx = blockIdx.x * 256 + threadIdx.x;
    if (idx >= 4 * 64 * 128) return;
    int L = idx >> 13, r = idx & 8191;
    int o = r >> 7, k = r & 127;
    pwk[idx] = (short)f2bf(pw[(size_t)L * 8320 + o * 130 + k]);
}
// DFT matrices: Wfg bf16 [48][128] (forward rfft over W); Winvbg bf16 [128][64] (irfft)
__global__ __launch_bounds__(256) void gen_dft_kernel(
    short* __restrict__ Wfg, short* __restrict__ Winvbg)
{
    int idx = blockIdx.x * 256 + threadIdx.x;
    if (idx < 48 * 128) {
        int n = idx >> 7, xx = idx & 127;
        float val = 0.f;
        if (n < 40) {
            int kx = n >> 1;
            float s, c;
            sincosf(6.283185307179586f * (float)((kx * xx) & 127) / 128.0f, &s, &c);
            val = (n & 1) ? -s : c;
        }
        Wfg[idx] = (short)f2bf(val);
    } else if (idx < 48 * 128 + 128 * 64) {
        int j = idx - 48 * 128;
        int xx = j >> 6, k = j & 63;
        float val = 0.f;
        if (k < 40) {
            int kx = k >> 1;
            if (kx == 0) {
                val = (k & 1) ? 0.f : (1.0f / 16384.0f);
            } else {
                float s, c;
                sincosf(6.283185307179586f * (float)((kx * xx) & 127) / 128.0f, &s, &c);
                val = ((k & 1) ? -s : c) * (2.0f / 16384.0f);
            }
        }
        Winvbg[j] = (short)f2bf(val);
    }
}

// ---------------- dft1 (MFMA): per bc, [128y x 128x] x [128x x 40] -> out1g bf16 [bc][40][128y]
__global__ __launch_bounds__(256) void dft1_mfma_kernel(
    const float* __restrict__ xin, const short* __restrict__ Wfg,
    short* __restrict__ out1g)
{
    __shared__ short img[128 * 128];   // 32KB, XOR-swizzled x8-groups
    int t = threadIdx.x;
    int bc = blockIdx.x;
    int lane = t & 63, w = t >> 6;

    const float* src = xin + (size_t)bc * HW;
#pragma unroll
    for (int i = 0; i < 8; ++i) {
        int chunk = i * 256 + t;          // 128y * 16 xgroups
        int y = chunk >> 4, x8 = chunk & 15;
        const float* p = src + y * 128 + x8 * 8;
        f32x4 v0 = *(const f32x4*)p, v1 = *(const f32x4*)(p + 4);
        int4 h = make_int4(pack2(v0[0], v0[1]), pack2(v0[2], v0[3]),
                           pack2(v1[0], v1[1]), pack2(v1[2], v1[3]));
        *(int4*)&img[y * 128 + ((x8 ^ (y & 7)) << 3)] = h;
    }

    short8 bF[3][4];
#pragma unroll
    for (int nf = 0; nf < 3; ++nf)
#pragma unroll
        for (int ks = 0; ks < 4; ++ks) {
            int n = nf * 16 + (lane & 15);
            int x0 = ks * 32 + (lane >> 4) * 8;
            bF[nf][ks] = *(const short8*)(Wfg + n * 128 + x0);
        }
    __syncthreads();

    f32x4 acc[2][3];
#pragma unroll
    for (int a = 0; a < 2; ++a)
#pragma unroll
        for (int b2 = 0; b2 < 3; ++b2) acc[a][b2] = (f32x4){0.f, 0.f, 0.f, 0.f};

#pragma unroll
    for (int ks = 0; ks < 4; ++ks)
#pragma unroll
        for (int mf = 0; mf < 2; ++mf) {
            int y = w * 32 + mf * 16 + (lane & 15);
            int x0 = ks * 32 + (lane >> 4) * 8;
            short8 aF = *(const short8*)&img[y * 128 + ((((x0 >> 3) ^ (y & 7))) << 3)];
#pragma unroll
            for (int nf = 0; nf < 3; ++nf)
                acc[mf][nf] = __builtin_amdgcn_mfma_f32_16x16x32_bf16(aF, bF[nf][ks], acc[mf][nf], 0, 0, 0);
        }

    short* ob = out1g + (size_t)bc * 5120;
#pragma unroll
    for (int mf = 0; mf < 2; ++mf)
#pragma unroll
        for (int nf = 0; nf < 3; ++nf) {
            int n = nf * 16 + (lane & 15);
            if (n < 40) {
                int y0 = w * 32 + mf * 16 + (lane >> 4) * 4;
                int2 h = make_int2(pack2(acc[mf][nf][0], acc[mf][nf][1]),
                                   pack2(acc[mf][nf][2], acc[mf][nf][3]));
                *(int2*)&ob[n * 128 + y0] = h;
            }
        }
}

// ---------------- dft2 (fp32, LDS-staged): out1g [bc][40][128y] -> fm float2 [bc][800]
__global__ __launch_bounds__(256) void dft2_kernel(
    const short* __restrict__ out1g, float2* __restrict__ fm)
{
    __shared__ float re[20][132], im[20][132];
    __shared__ float tc[128], ts[128];
    int t = threadIdx.x;
    int bc = blockIdx.x;
    if (t < 128) { float s, c; sincosf(6.283185307179586f * (float)t / 128.0f, &s, &c); tc[t] = c; ts[t] = s; }
    const u32* src = (const u32*)(out1g + (size_t)bc * 5120);
    for (int i = t; i < 2560; i += 256) {
        u32 u = src[i];
        int n = i >> 6, y2 = (i & 63) * 2;
        float* pl = (n & 1) ? &im[n >> 1][0] : &re[n >> 1][0];
        pl[y2] = bf2f(u & 0xffffu);
        pl[y2 + 1] = bf2f(u >> 16);
    }
    __syncthreads();
    float2* fmo = fm + (size_t)bc * 800;
    for (int oidx = t; oidx < 800; oidx += 256) {
        int kyi = oidx / 20, kx = oidx - kyi * 20;
        int ky = kyi + ((kyi >= 20) ? 88 : 0);
        float r = 0.f, q = 0.f;
        for (int y = 0; y < 128; ++y) {
            int tt = (ky * y) & 127;
            float c = tc[tt], s = ts[tt];
            float ar = re[kx][y], ai = im[kx][y];
            r += ar * c + ai * s;
            q += ai * c - ar * s;
        }
        fmo[oidx] = make_float2(r, q);
    }
}

// ---------------- per-mode 64x64 complex multiply (unchanged) ---------------------
__global__ __launch_bounds__(256) void specmul_kernel(
    const float2* __restrict__ fm,
    const float* __restrict__ w1r, const float* __restrict__ w1i,
    const float* __restrict__ w2r, const float* __restrict__ w2i,
    float2* __restrict__ fm2, int nb64)
{
    __shared__ float2 lx[32 * 64];
    __shared__ float2 lw[64 * 64];
    int t = threadIdx.x;
    int mode = blockIdx.x;
    int region = mode / 400;
    int km = mode % 400;
    int kyi = region * 20 + (km / 20);
    int kx = km % 20;
    const float* wr = region ? w2r : w1r;
    const float* wi = region ? w2i : w1i;
    int modeoff = kyi * 20 + kx;
    for (int n = t; n < nb64; n += 256)
        lx[n] = fm[(size_t)n * 800 + modeoff];
    for (int n = t; n < 4096; n += 256) {
        size_t a = (size_t)n * 400 + km;
        lw[n] = make_float2(wr[a], wi[a]);
    }
    __syncthreads();
    for (int n = t; n < nb64; n += 256) {
        int b = n >> 6, o = n & 63;
        float re = 0.f, imv = 0.f;
        const float2* xb = lx + b * 64;
#pragma unroll 8
        for (int i = 0; i < 64; ++i) {
            float2 a = xb[i];
            float2 w = lw[i * 64 + o];
            re += a.x * w.x - a.y * w.y;
            imv += a.x * w.y + a.y * w.x;
        }
        fm2[(size_t)n * 800 + modeoff] = make_float2(re, imv);
    }
}

// ---------------- invA (fp32, LDS-staged): fm2 [bc][800] -> g bf16 [bc][y][48] -----
__global__ __launch_bounds__(256) void invA_kernel(
    const float2* __restrict__ fm2, short* __restrict__ g)
{
    __shared__ float rf[40][21], qf[40][21];
    __shared__ float tc[128], ts[128];
    int t = threadIdx.x;
    int bc = blockIdx.x;
    if (t < 128) { float s, c; sincosf(6.283185307179586f * (float)t / 128.0f, &s, &c); tc[t] = c; ts[t] = s; }
    const float2* src = fm2 + (size_t)bc * 800;
    for (int i = t; i < 800; i += 256) {
        float2 v = src[i];
        int kyi = i / 20, kx = i - kyi * 20;
        rf[kyi][kx] = v.x;
        qf[kyi][kx] = v.y;
    }
    __syncthreads();
    for (int oidx = t; oidx < 2560; oidx += 256) {
        int y = oidx / 20, kx = oidx - y * 20;
        float r = 0.f, q = 0.f;
#pragma unroll 8
        for (int kyi = 0; kyi < 40; ++kyi) {
            int ky = kyi + ((kyi >= 20) ? 88 : 0);
            int tt = (ky * y) & 127;
            float c = tc[tt], s = ts[tt];
            float ar = rf[kyi][kx], ai = qf[kyi][kx];
            r += ar * c - ai * s;
            q += ar * s + ai * c;
        }
        u32* grow = (u32*)(g + ((size_t)bc * 128 + y) * 48);
        grow[kx] = pack2(r, q);
        if (kx < 4) grow[20 + kx] = 0u;   // zero-pad k 40..47
    }
}

// ---------------- invB (MFMA): per (b, 4-y tile): M=c(64) N=x(128) K=40pad64 ------
// out: s1g bf16 [b][y][x][c]
__global__ __launch_bounds__(256) void invB_mfma_kernel(
    const short* __restrict__ g, const short* __restrict__ Winvbg,
    short* __restrict__ s1g)
{
    __shared__ short A[4 * 64 * 64];   // 32KB: [y][c][k64] swizzled
    int t = threadIdx.x;
    int tile = blockIdx.x;             // 0..31
    int b = blockIdx.y;
    int lane = t & 63, w = t >> 6;
    int y0 = tile * 4;

    short8 bF[8][2];
#pragma unroll
    for (int nf = 0; nf < 8; ++nf)
#pragma unroll
        for (int ks = 0; ks < 2; ++ks) {
            int xx = nf * 16 + (lane & 15);
            int k0 = ks * 32 + (lane >> 4) * 8;
            bF[nf][ks] = *(const short8*)(Winvbg + xx * 64 + k0);
        }

    const short* gb = g + (size_t)b * 64 * 128 * 48;
    short8 vz = {0, 0, 0, 0, 0, 0, 0, 0};
#pragma unroll
    for (int i = 0; i < 8; ++i) {
        int chunk = i * 256 + t;          // 4y*64c*8grp
        int y = chunk >> 9, c = (chunk >> 3) & 63, g8 = chunk & 7;
        short8 v = (g8 < 6) ? *(const short8*)(gb + ((size_t)c * 128 + y0 + y) * 48 + g8 * 8) : vz;
        *(short8*)&A[((y * 64 + c) << 6) + ((g8 ^ (c & 7)) << 3)] = v;
    }
    __syncthreads();

    int c0 = w * 16;
#pragma unroll
    for (int y = 0; y < 4; ++y) {
        int c = c0 + (lane & 15);
        int base = (y * 64 + c) << 6;
        short8 aF0 = *(const short8*)&A[base + (((lane >> 4) ^ (c & 7)) << 3)];
        short8 aF1 = *(const short8*)&A[base + (((4 + (lane >> 4)) ^ (c & 7)) << 3)];
        short* orow = s1g + ((size_t)(b * 128 + y0 + y)) * 128 * 64;
#pragma unroll
        for (int nf = 0; nf < 8; ++nf) {
            f32x4 acc = (f32x4){0.f, 0.f, 0.f, 0.f};
            acc = __builtin_amdgcn_mfma_f32_16x16x32_bf16(aF0, bF[nf][0], acc, 0, 0, 0);
            acc = __builtin_amdgcn_mfma_f32_16x16x32_bf16(aF1, bF[nf][1], acc, 0, 0, 0);
            int xx = nf * 16 + (lane & 15);
            int cw = c0 + (lane >> 4) * 4;
            int2 h = make_int2(pack2(acc[0], acc[1]), pack2(acc[2], acc[3]));
            *(int2*)&orow[xx * 64 + cw] = h;
        }
    }
}

// ---------------- conv 3x3 (MFMA) -> c2g bf16 [b][y][x][c] -------------------------
__global__ __launch_bounds__(256) void conv3_mfma_kernel(
    const float* __restrict__ xin,
    const short* __restrict__ wpk,
    const float* __restrict__ cb,
    short* __restrict__ c2g)
{
    __shared__ short xlds[3 * 128 * 64];
    int t = threadIdx.x;
    int y = blockIdx.x;
    int b = blockIdx.y;
    int lane = t & 63, wid = t >> 6;

    const float* xb = xin + (size_t)b * 64 * HW;
#pragma unroll 4
    for (int p = 0; p < 48; ++p) {
        int linear = p * 256 + t;
        int x = linear & 127;
        int ip = (linear >> 7) & 31;
        int row = linear >> 12;
        int i = ip * 2;
        int yy = (y + row + 127) & 127;
        float f0 = xb[(size_t)i * HW + yy * 128 + x];
        float f1 = xb[(size_t)(i + 1) * HW + yy * 128 + x];
        unsigned h = f2bf(f0) | (f2bf(f1) << 16);
        int gg = (i >> 3) ^ (x & 7);
        *(unsigned*)&xlds[(row * 128 + x) * 64 + gg * 8 + (i & 7)] = h;
    }

    int o0 = wid * 16;
    const short* wbase = wpk + (size_t)(o0 + (lane & 15)) * 576 + (lane >> 4) * 8;
    short8 aF[18];
#pragma unroll
    for (int s = 0; s < 18; ++s)
        aF[s] = *(const short8*)(wbase + s * 32);

    __syncthreads();

    f32x4 acc[8];
#pragma unroll
    for (int f = 0; f < 8; ++f) acc[f] = (f32x4){0.f, 0.f, 0.f, 0.f};
#pragma unroll
    for (int s = 0; s < 18; ++s) {
        const int tap = s >> 1;
        const int ky = tap / 3, kx = tap % 3;
        int ig = (s & 1) * 4 + (lane >> 4);
#pragma unroll
        for (int f = 0; f < 8; ++f) {
            int xx = (f * 16 + (lane & 15) + kx + 127) & 127;
            int off = (ky * 128 + xx) * 64 + ((ig ^ (xx & 7)) << 3);
            short8 bG = *(const short8*)&xlds[off];
            acc[f] = __builtin_amdgcn_mfma_f32_16x16x32_bf16(aF[s], bG, acc[f], 0, 0, 0);
        }
    }

    int ob = o0 + (lane >> 4) * 4;
    float bias0 = cb[ob], bias1 = cb[ob + 1], bias2 = cb[ob + 2], bias3 = cb[ob + 3];
    short* orow = c2g + ((size_t)(b * 128 + y)) * 128 * 64;
#pragma unroll
    for (int f = 0; f < 8; ++f) {
        int x = f * 16 + (lane & 15);
        int2 h = make_int2(pack2(acc[f][0] + bias0, acc[f][1] + bias1),
                           pack2(acc[f][2] + bias2, acc[f][3] + bias3));
        *(int2*)&orow[x * 64 + ob] = h;
    }
}

// ---------------- combine (MFMA): xo=[s1;c2], prods; xnew = xold + tanh(pw.xo+pb) --
__global__ __launch_bounds__(256) void combine_mfma_kernel(
    const short* __restrict__ s1g,   // [b][y][x][64] bf16
    const short* __restrict__ c2g,   // [b][y][x][64] bf16
    const short* __restrict__ pwk,   // [64][128] bf16 layer base
    const float* __restrict__ pw,    // fp32 (64,130) layer base (cols 128/129)
    const float* __restrict__ pb,
    const float* __restrict__ xold,
    float* __restrict__ xnew)
{
    __shared__ short S1[128 * 64];   // 16KB swizzled [x][c]
    __shared__ short C2[128 * 64];   // 16KB
    __shared__ float2 pr[128];
    int t = threadIdx.x;
    int y = blockIdx.x;
    int b = blockIdx.y;
    int lane = t & 63, w = t >> 6;

    const short* s1b = s1g + ((size_t)(b * 128 + y)) * 128 * 64;
    const short* c2b = c2g + ((size_t)(b * 128 + y)) * 128 * 64;
#pragma unroll
    for (int i = 0; i < 4; ++i) {
        int chunk = i * 256 + t;       // 1024 chunks of 8 shorts
        int xx = chunk >> 3, c8 = chunk & 7;
        int dst = xx * 64 + ((c8 ^ (xx & 7)) << 3);
        *(short8*)&S1[dst] = *(const short8*)(s1b + chunk * 8);
        *(short8*)&C2[dst] = *(const short8*)(c2b + chunk * 8);
    }
    if (t < 128) {
        const short* sp = s1b + t * 64;
        float v0 = bf2f((u32)(unsigned short)sp[0]);
        float v1 = bf2f((u32)(unsigned short)sp[1]);
        float v2 = bf2f((u32)(unsigned short)sp[2]);
        float v3 = bf2f((u32)(unsigned short)sp[3]);
        pr[t] = make_float2(v0 * v2, v1 * v3);
    }

    short8 bF[4][4];
#pragma unroll
    for (int nf = 0; nf < 4; ++nf)
#pragma unroll
        for (int ks = 0; ks < 4; ++ks) {
            int o = nf * 16 + (lane & 15);
            int k0 = ks * 32 + (lane >> 4) * 8;
            bF[nf][ks] = *(const short8*)(pwk + o * 128 + k0);
        }
    __syncthreads();

    f32x4 acc[2][4];
#pragma unroll
    for (int a = 0; a < 2; ++a)
#pragma unroll
        for (int b2 = 0; b2 < 4; ++b2) acc[a][b2] = (f32x4){0.f, 0.f, 0.f, 0.f};

#pragma unroll
    for (int ks = 0; ks < 4; ++ks)
#pragma unroll
        for (int mf = 0; mf < 2; ++mf) {
            int xx = w * 32 + mf * 16 + (lane & 15);
            int k0 = ks * 32 + (lane >> 4) * 8;
            const short* src = (ks < 2) ? &S1[xx * 64 + ((((k0 >> 3) ^ (xx & 7))) << 3)]
                                        : &C2[xx * 64 + (((((k0 - 64) >> 3) ^ (xx & 7))) << 3)];
            short8 aF = *(const short8*)src;
#pragma unroll
            for (int nf = 0; nf < 4; ++nf)
                acc[mf][nf] = __builtin_amdgcn_mfma_f32_16x16x32_bf16(aF, bF[nf][ks], acc[mf][nf], 0, 0, 0);
        }

#pragma unroll
    for (int mf = 0; mf < 2; ++mf) {
        int xr = w * 32 + mf * 16 + (lane >> 4) * 4;
        float2 prv0 = pr[xr], prv1 = pr[xr + 1], prv2 = pr[xr + 2], prv3 = pr[xr + 3];
#pragma unroll
        for (int nf = 0; nf < 4; ++nf) {
            int o = nf * 16 + (lane & 15);
            const float* pwrow = pw + o * 130;
            float pw128 = pwrow[128], pw129 = pwrow[129], pbv = pb[o];
            size_t off = ((size_t)(b * 64 + o)) * HW + y * 128 + xr;
            f32x4 xov = *(const f32x4*)(xold + off);
            f32x4 res;
            res[0] = xov[0] + tanhf(acc[mf][nf][0] + pbv + pw128 * prv0.x + pw129 * prv0.y);
            res[1] = xov[1] + tanhf(acc[mf][nf][1] + pbv + pw128 * prv1.x + pw129 * prv1.y);
            res[2] = xov[2] + tanhf(acc[mf][nf][2] + pbv + pw128 * prv2.x + pw129 * prv2.y);
            res[3] = xov[3] + tanhf(acc[mf][nf][3] + pbv + pw128 * prv3.x + pw129 * prv3.y);
            *(f32x4*)(xnew + off) = res;
        }
    }
}

// ---------------- fc1 head: 64 -> gelu(128) -> 1 ---------------------------------
__global__ __launch_bounds__(256) void fc1_kernel(
    const float* __restrict__ xin,
    const float* __restrict__ w1, const float* __restrict__ b1,
    const float* __restrict__ w2, const float* __restrict__ b2,
    float* __restrict__ out)
{
    __shared__ float lw1[128 * 64];
    __shared__ float lb1[128], lw2[128];
    int t = threadIdx.x;
    for (int n = t; n < 128 * 64; n += 256) lw1[n] = w1[n];
    if (t < 128) { lb1[t] = b1[t]; lw2[t] = w2[t]; }
    __syncthreads();
    int gid = blockIdx.x * 256 + t;
    int b = gid >> 14, p = gid & 16383;
    const float* xb = xin + (size_t)b * 64 * HW + p;
    float v[64];
#pragma unroll
    for (int c = 0; c < 64; ++c) v[c] = xb[(size_t)c * HW];
    float o = b2[0];
    for (int m = 0; m < 128; ++m) {
        float s = lb1[m];
#pragma unroll
        for (int c = 0; c < 64; ++c) s += lw1[m * 64 + c] * v[c];
        o += lw2[m] * gelu_tanh(s);
    }
    out[gid] = o;
}

extern "C" void kernel_launch(void* const* d_in, const int* in_sizes, int n_in,
                              void* d_out, int out_size, void* d_ws, size_t ws_size,
                              hipStream_t stream) {
    const float* x      = (const float*)d_in[0];
    const float* qa     = (const float*)d_in[1];
    const float* qb     = (const float*)d_in[2];
    const float* fc0w1  = (const float*)d_in[3];
    const float* fc0b1  = (const float*)d_in[4];
    const float* fc0w2  = (const float*)d_in[5];
    const float* fc0b2  = (const float*)d_in[6];
    const float* sw1r   = (const float*)d_in[7];
    const float* sw1i   = (const float*)d_in[8];
    const float* sw2r   = (const float*)d_in[9];
    const float* sw2i   = (const float*)d_in[10];
    const float* cw     = (const float*)d_in[11];
    const float* cb     = (const float*)d_in[12];
    const float* pw     = (const float*)d_in[13];
    const float* pb     = (const float*)d_in[14];
    const float* fc1w1  = (const float*)d_in[15];
    const float* fc1b1  = (const float*)d_in[16];
    const float* fc1w2  = (const float*)d_in[17];
    const float* fc1b2  = (const float*)d_in[18];

    // const packs (floats): wpk 73728 + pwk 16384 + Wfg 3072 + Winvbg 4096
    const size_t WPK_F = 73728, PWK_F = 16384, WFG_F = 3072, WIB_F = 4096;
    const size_t CONST_F = WPK_F + PWK_F + WFG_F + WIB_F;
    // per-batch floats: xA+xB 2*1048576, s1g 524288, c2g 524288, out1g 163840,
    // g 196608, fm 102400, fm2 102400
    const size_t PER_B_F = 2u * 1048576u + 2u * 524288u + 163840u + 196608u + 2u * 102400u;
    int NB = 32;
    while (NB > 1 && ((size_t)NB * PER_B_F + CONST_F) * 4 > ws_size) NB >>= 1;
    if (((size_t)NB * PER_B_F + CONST_F) * 4 > ws_size) return;

    short* wpk    = (short*)d_ws;
    short* pwk    = (short*)((float*)d_ws + WPK_F);
    short* Wfg    = (short*)((float*)d_ws + WPK_F + PWK_F);
    short* Winvbg = (short*)((float*)d_ws + WPK_F + PWK_F + WFG_F);
    float* base   = (float*)d_ws + CONST_F;

    float*  xA    = base;
    float*  xB    = xA + (size_t)NB * 1048576u;
    short*  s1g   = (short*)(xB + (size_t)NB * 1048576u);
    short*  c2g   = s1g + (size_t)NB * 1048576u;          // shorts
    short*  out1g = c2g + (size_t)NB * 1048576u;
    short*  g     = out1g + (size_t)NB * 327680u;
    float2* fm    = (float2*)(g + (size_t)NB * 393216u);
    float2* fm2   = fm + (size_t)NB * 51200u;

    packw_kernel<<<576, 256, 0, stream>>>(cw, wpk);
    packpw_kernel<<<128, 256, 0, stream>>>(pw, pwk);
    gen_dft_kernel<<<56, 256, 0, stream>>>(Wfg, Winvbg);

    for (int b0 = 0; b0 < 32; b0 += NB) {
        front_kernel<<<NB * 64, 256, 0, stream>>>(
            x + (size_t)b0 * 10 * HW, qa, qb, fc0w1, fc0b1, fc0w2, fc0b2, xA);

        float* xcur = xA;
        float* xnxt = xB;
        for (int L = 0; L < 4; ++L) {
            const size_t swoff = (size_t)L * 1638400;
            dft1_mfma_kernel<<<NB * 64, 256, 0, stream>>>(xcur, Wfg, out1g);
            dft2_kernel<<<NB * 64, 256, 0, stream>>>(out1g, fm);
            specmul_kernel<<<800, 256, 0, stream>>>(fm, sw1r + swoff, sw1i + swoff,
                                                    sw2r + swoff, sw2i + swoff, fm2, NB * 64);
            invA_kernel<<<NB * 64, 256, 0, stream>>>(fm2, g);
            invB_mfma_kernel<<<dim3(32, NB), 256, 0, stream>>>(g, Winvbg, s1g);
            conv3_mfma_kernel<<<dim3(128, NB), 256, 0, stream>>>(
                xcur, wpk + (size_t)L * 36864, cb + (size_t)L * 64, c2g);
            combine_mfma_kernel<<<dim3(128, NB), 256, 0, stream>>>(
                s1g, c2g, pwk + (size_t)L * 8192, pw + (size_t)L * 8320,
                pb + (size_t)L * 64, xcur, xnxt);
            float* tmp = xcur; xcur = xnxt; xnxt = tmp;
        }

        fc1_kernel<<<NB * 64, 256, 0, stream>>>(
            xcur, fc1w1, fc1b1, fc1w2, fc1b2, (float*)d_out + (size_t)b0 * HW);
    }
}

// Round 5
// 1965.310 us; speedup vs baseline: 4.4256x; 1.4064x over previous
//
#include <hip/hip_runtime.h>
#include <math.h>

#define HW 16384   // 128*128

typedef __attribute__((ext_vector_type(8))) short short8;
typedef __attribute__((ext_vector_type(4))) float f32x4;
typedef unsigned int u32;

__device__ __forceinline__ float gelu_tanh(float x) {
    float x3 = x * x * x;
    float t = tanhf(0.7978845608028654f * (x + 0.044715f * x3));
    return 0.5f * x * (1.0f + t);
}

__device__ __forceinline__ u32 f2bf(float f) {
    u32 u = __builtin_bit_cast(u32, f);
    return (u + 0x7FFFu + ((u >> 16) & 1u)) >> 16;   // RNE bf16
}
__device__ __forceinline__ u32 pack2(float a, float b) {
    return f2bf(a) | (f2bf(b) << 16);
}

// ---------------- const packs ------------------------------------------------------
// conv weights: (L,o,i,ky,kx) -> bf16 [L][o][tap*64+i]
__global__ __launch_bounds__(256) void packw_kernel(
    const float* __restrict__ cw, short* __restrict__ wpk)
{
    int idx = blockIdx.x * 256 + threadIdx.x;
    if (idx >= 4 * 64 * 576) return;
    int L = idx / 36864, r = idx % 36864;
    int o = r / 576, k = r % 576;
    int tap = k >> 6, i = k & 63;
    wpk[idx] = (short)f2bf(cw[((size_t)(L * 64 + o) * 64 + i) * 9 + tap]);
}
// pw first 128 cols: bf16 [L][o][128]
__global__ __launch_bounds__(256) void packpw_kernel(
    const float* __restrict__ pw, short* __restrict__ pwk)
{
    int idx = blockIdx.x * 256 + threadIdx.x;
    if (idx >= 4 * 64 * 128) return;
    int L = idx >> 13, r = idx & 8191;
    int o = r >> 7, k = r & 127;
    pwk[idx] = (short)f2bf(pw[(size_t)L * 8320 + o * 130 + k]);
}
// fc weights: w1k [128][32] (K-pad), w2k [48][128], f1wk [128][64]
__global__ __launch_bounds__(256) void packfc_kernel(
    const float* __restrict__ fc0w1, const float* __restrict__ fc0w2,
    const float* __restrict__ fc1w1,
    short* __restrict__ w1k, short* __restrict__ w2k, short* __restrict__ f1wk)
{
    int i = blockIdx.x * 256 + threadIdx.x;
    if (i < 4096) {
        int m = i >> 5, k = i & 31;
        w1k[i] = (short)(k < 16 ? f2bf(fc0w1[m * 16 + k]) : 0);
    } else if (i < 10240) {
        int j = i - 4096; int o = j >> 7, m = j & 127;
        w2k[j] = (short)f2bf(fc0w2[o * 128 + m]);
    } else if (i < 18432) {
        int j = i - 10240; int m = j >> 6, c = j & 63;
        f1wk[j] = (short)f2bf(fc1w1[m * 64 + c]);
    }
}
// DFT matrices: Wfg [48][128], Winvbg [128][64], Tfy [80][128], Tiy [128][96]
__global__ __launch_bounds__(256) void gen_dft_kernel(
    short* __restrict__ Wfg, short* __restrict__ Winvbg,
    short* __restrict__ Tfy, short* __restrict__ Tiy)
{
    int idx = blockIdx.x * 256 + threadIdx.x;
    if (idx < 6144) {
        int n = idx >> 7, xx = idx & 127;
        float val = 0.f;
        if (n < 40) {
            int kx = n >> 1;
            float s, c;
            sincosf(6.283185307179586f * (float)((kx * xx) & 127) / 128.0f, &s, &c);
            val = (n & 1) ? -s : c;
        }
        Wfg[idx] = (short)f2bf(val);
    } else if (idx < 14336) {
        int j = idx - 6144;
        int xx = j >> 6, k = j & 63;
        float val = 0.f;
        if (k < 40) {
            int kx = k >> 1;
            if (kx == 0) {
                val = (k & 1) ? 0.f : (1.0f / 16384.0f);
            } else {
                float s, c;
                sincosf(6.283185307179586f * (float)((kx * xx) & 127) / 128.0f, &s, &c);
                val = ((k & 1) ? -s : c) * (2.0f / 16384.0f);
            }
        }
        Winvbg[j] = (short)f2bf(val);
    } else if (idx < 24576) {
        int j = idx - 14336;      // Tfy [80][128]
        int q = j >> 7, yy = j & 127;
        int kyi = q >> 1;
        int ky = kyi + ((kyi >= 20) ? 88 : 0);
        float s, c;
        sincosf(6.283185307179586f * (float)((ky * yy) & 127) / 128.0f, &s, &c);
        Tfy[j] = (short)f2bf((q & 1) ? s : c);
    } else if (idx < 36864) {
        int j = idx - 24576;      // Tiy [128][96]
        int yy = j / 96, q = j - yy * 96;
        float val = 0.f;
        if (q < 80) {
            int kyi = q >> 1;
            int ky = kyi + ((kyi >= 20) ? 88 : 0);
            float s, c;
            sincosf(6.283185307179586f * (float)((ky * yy) & 127) / 128.0f, &s, &c);
            val = (q & 1) ? s : c;
        }
        Tiy[j] = (short)f2bf(val);
    }
}

// ---------------- front (MFMA): grid+quad+fc0 lift -> xbuf fp32 + xb16 c-last ----
__global__ __launch_bounds__(256) void front_mfma_kernel(
    const float* __restrict__ x,          // (NB,10,128,128) chunk base
    const float* __restrict__ qa, const float* __restrict__ qb,
    const short* __restrict__ w1k, const float* __restrict__ b1,
    const short* __restrict__ w2k, const float* __restrict__ b2,
    float* __restrict__ xbuf, short* __restrict__ xb16)
{
    __shared__ short V[128 * 40];     // [x][k] pad40
    __shared__ short A2[128 * 136];   // [x][m] pad136
    __shared__ float lqa[48], lqb[48], lb1[128], lb2[48];
    int t = threadIdx.x;
    int y = blockIdx.x, b = blockIdx.y;
    int lane = t & 63, w = t >> 6;

    if (t < 48) { lqa[t] = qa[t]; lqb[t] = qb[t]; lb2[t] = b2[t]; }
    if (t >= 128) lb1[t - 128] = b1[t - 128];
    __syncthreads();

    if (t < 128) {
        int xx = t;
        float v[16];
        const float* xsrc = x + (size_t)b * 10 * HW + y * 128 + xx;
#pragma unroll
        for (int c = 0; c < 10; ++c) v[c] = xsrc[c * HW];
        v[10] = (float)y * (1.0f / 127.0f);
        v[11] = (float)xx * (1.0f / 127.0f);
#pragma unroll
        for (int o = 0; o < 4; ++o) {
            float sa = 0.f, sb = 0.f;
#pragma unroll
            for (int c = 0; c < 12; ++c) { sa += lqa[o * 12 + c] * v[c]; sb += lqb[o * 12 + c] * v[c]; }
            v[12 + o] = sa * sb;
        }
        u32* vr = (u32*)&V[xx * 40];
#pragma unroll
        for (int j = 0; j < 8; ++j) vr[j] = pack2(v[2 * j], v[2 * j + 1]);
#pragma unroll
        for (int j = 8; j < 16; ++j) vr[j] = 0u;
        float* ob = xbuf + (size_t)b * 64 * HW + y * 128 + xx;
#pragma unroll
        for (int c = 0; c < 16; ++c) ob[(size_t)c * HW] = v[c];
        u32* hb = (u32*)&xb16[(((size_t)b * 128 + y) * 128 + xx) * 64];
#pragma unroll
        for (int j = 0; j < 8; ++j) hb[j] = vr[j];
    }
    __syncthreads();

    // GEMM-a: h = gelu(W1*v + b1): M=m(2 mt/wave), N=x(8), K=32
    {
        short8 aF[2];
#pragma unroll
        for (int mi = 0; mi < 2; ++mi)
            aF[mi] = *(const short8*)(w1k + ((w * 2 + mi) * 16 + (lane & 15)) * 32 + (lane >> 4) * 8);
        f32x4 acc[2][8];
#pragma unroll
        for (int mi = 0; mi < 2; ++mi)
#pragma unroll
            for (int nf = 0; nf < 8; ++nf) acc[mi][nf] = (f32x4){0.f, 0.f, 0.f, 0.f};
#pragma unroll
        for (int nf = 0; nf < 8; ++nf) {
            int xx = nf * 16 + (lane & 15);
            short8 bF = *(const short8*)&V[xx * 40 + (lane >> 4) * 8];
#pragma unroll
            for (int mi = 0; mi < 2; ++mi)
                acc[mi][nf] = __builtin_amdgcn_mfma_f32_16x16x32_bf16(aF[mi], bF, acc[mi][nf], 0, 0, 0);
        }
#pragma unroll
        for (int mi = 0; mi < 2; ++mi) {
            int m0 = (w * 2 + mi) * 16 + (lane >> 4) * 4;
            float bb0 = lb1[m0], bb1 = lb1[m0 + 1], bb2 = lb1[m0 + 2], bb3 = lb1[m0 + 3];
#pragma unroll
            for (int nf = 0; nf < 8; ++nf) {
                int xx = nf * 16 + (lane & 15);
                float h0 = gelu_tanh(acc[mi][nf][0] + bb0);
                float h1 = gelu_tanh(acc[mi][nf][1] + bb1);
                float h2 = gelu_tanh(acc[mi][nf][2] + bb2);
                float h3 = gelu_tanh(acc[mi][nf][3] + bb3);
                *(int2*)&A2[xx * 136 + m0] = make_int2(pack2(h0, h1), pack2(h2, h3));
            }
        }
    }
    __syncthreads();

    // GEMM-b: lift = W2*h + b2: M=o(3), N=x(2 nt/wave), K=128
    {
        short8 aF[3][4];
#pragma unroll
        for (int mt = 0; mt < 3; ++mt)
#pragma unroll
            for (int ks = 0; ks < 4; ++ks)
                aF[mt][ks] = *(const short8*)(w2k + (mt * 16 + (lane & 15)) * 128 + ks * 32 + (lane >> 4) * 8);
#pragma unroll
        for (int ni = 0; ni < 2; ++ni) {
            int nt = w * 2 + ni;
            int xx = nt * 16 + (lane & 15);
            f32x4 acc[3];
#pragma unroll
            for (int mt = 0; mt < 3; ++mt) acc[mt] = (f32x4){0.f, 0.f, 0.f, 0.f};
#pragma unroll
            for (int ks = 0; ks < 4; ++ks) {
                short8 bF = *(const short8*)&A2[xx * 136 + ks * 32 + (lane >> 4) * 8];
#pragma unroll
                for (int mt = 0; mt < 3; ++mt)
                    acc[mt] = __builtin_amdgcn_mfma_f32_16x16x32_bf16(aF[mt][ks], bF, acc[mt], 0, 0, 0);
            }
#pragma unroll
            for (int mt = 0; mt < 3; ++mt) {
                int o0 = mt * 16 + (lane >> 4) * 4;
                float r0 = acc[mt][0] + lb2[o0], r1 = acc[mt][1] + lb2[o0 + 1];
                float r2 = acc[mt][2] + lb2[o0 + 2], r3 = acc[mt][3] + lb2[o0 + 3];
                float* ob = xbuf + (size_t)b * 64 * HW + (size_t)(16 + o0) * HW + y * 128 + xx;
                ob[0] = r0; ob[HW] = r1; ob[2 * HW] = r2; ob[3 * HW] = r3;
                *(int2*)&xb16[(((size_t)b * 128 + y) * 128 + xx) * 64 + 16 + o0] =
                    make_int2(pack2(r0, r1), pack2(r2, r3));
            }
        }
    }
}

// ---------------- dft1 (MFMA): per bc, [128y x 128x] x Wf -> out1g bf16 [bc][40][128y]
__global__ __launch_bounds__(256) void dft1_mfma_kernel(
    const float* __restrict__ xin, const short* __restrict__ Wfg,
    short* __restrict__ out1g)
{
    __shared__ short img[128 * 128];
    int t = threadIdx.x;
    int bc = blockIdx.x;
    int lane = t & 63, w = t >> 6;

    const float* src = xin + (size_t)bc * HW;
#pragma unroll
    for (int i = 0; i < 8; ++i) {
        int chunk = i * 256 + t;
        int y = chunk >> 4, x8 = chunk & 15;
        const float* p = src + y * 128 + x8 * 8;
        f32x4 v0 = *(const f32x4*)p, v1 = *(const f32x4*)(p + 4);
        int4 h = make_int4(pack2(v0[0], v0[1]), pack2(v0[2], v0[3]),
                           pack2(v1[0], v1[1]), pack2(v1[2], v1[3]));
        *(int4*)&img[y * 128 + ((x8 ^ (y & 7)) << 3)] = h;
    }

    short8 bF[3][4];
#pragma unroll
    for (int nf = 0; nf < 3; ++nf)
#pragma unroll
        for (int ks = 0; ks < 4; ++ks) {
            int n = nf * 16 + (lane & 15);
            bF[nf][ks] = *(const short8*)(Wfg + n * 128 + ks * 32 + (lane >> 4) * 8);
        }
    __syncthreads();

    f32x4 acc[2][3];
#pragma unroll
    for (int a = 0; a < 2; ++a)
#pragma unroll
        for (int b2 = 0; b2 < 3; ++b2) acc[a][b2] = (f32x4){0.f, 0.f, 0.f, 0.f};

#pragma unroll
    for (int ks = 0; ks < 4; ++ks)
#pragma unroll
        for (int mf = 0; mf < 2; ++mf) {
            int y = w * 32 + mf * 16 + (lane & 15);
            int x0 = ks * 32 + (lane >> 4) * 8;
            short8 aF = *(const short8*)&img[y * 128 + ((((x0 >> 3) ^ (y & 7))) << 3)];
#pragma unroll
            for (int nf = 0; nf < 3; ++nf)
                acc[mf][nf] = __builtin_amdgcn_mfma_f32_16x16x32_bf16(aF, bF[nf][ks], acc[mf][nf], 0, 0, 0);
        }

    short* ob = out1g + (size_t)bc * 5120;
#pragma unroll
    for (int mf = 0; mf < 2; ++mf)
#pragma unroll
        for (int nf = 0; nf < 3; ++nf) {
            int n = nf * 16 + (lane & 15);
            if (n < 40) {
                int y0 = w * 32 + mf * 16 + (lane >> 4) * 4;
                *(int2*)&ob[n * 128 + y0] = make_int2(pack2(acc[mf][nf][0], acc[mf][nf][1]),
                                                      pack2(acc[mf][nf][2], acc[mf][nf][3]));
            }
        }
}

// ---------------- dft2 (MFMA): out1g -> fm [bc][800] fp32 --------------------------
__global__ __launch_bounds__(256) void dft2_mfma_kernel(
    const short* __restrict__ out1g, const short* __restrict__ Tfy,
    float2* __restrict__ fm)
{
    __shared__ short S[48 * 136];    // [n][y] pad136
    int t = threadIdx.x;
    int bc = blockIdx.x;
    int lane = t & 63, w = t >> 6;
    const short8* src = (const short8*)(out1g + (size_t)bc * 5120);
#pragma unroll
    for (int i = 0; i < 3; ++i) {
        int c = i * 256 + t;
        if (c < 640) {
            int n = c >> 4, y0 = (c & 15) * 8;
            *(short8*)&S[n * 136 + y0] = src[c];
        }
    }
    for (int i = t; i < 544; i += 256) ((u32*)S)[2720 + i] = 0u;  // rows 40..47
    __syncthreads();

    float2* fmo = fm + (size_t)bc * 800;
#pragma unroll
    for (int pi = 0; pi < 4; ++pi) {
        int p = w + pi * 4;
        if (p < 15) {
            int mt = p / 3, nt = p % 3;
            f32x4 acc = (f32x4){0.f, 0.f, 0.f, 0.f};
#pragma unroll
            for (int ks = 0; ks < 4; ++ks) {
                short8 aF = *(const short8*)(Tfy + (mt * 16 + (lane & 15)) * 128 + ks * 32 + (lane >> 4) * 8);
                short8 bF = *(const short8*)&S[(nt * 16 + (lane & 15)) * 136 + ks * 32 + (lane >> 4) * 8];
                acc = __builtin_amdgcn_mfma_f32_16x16x32_bf16(aF, bF, acc, 0, 0, 0);
            }
            float p0 = __shfl_xor(acc[0], 1), p1 = __shfl_xor(acc[1], 1);
            float p2 = __shfl_xor(acc[2], 1), p3 = __shfl_xor(acc[3], 1);
            int l15 = lane & 15;
            if (!(l15 & 1)) {
                int kx = nt * 8 + (l15 >> 1);
                if (kx < 20) {
                    int kyi0 = mt * 8 + ((lane >> 4) << 1);
                    fmo[kyi0 * 20 + kx] = make_float2(acc[0] + p1, p0 - acc[1]);
                    fmo[(kyi0 + 1) * 20 + kx] = make_float2(acc[2] + p3, p2 - acc[3]);
                }
            }
        }
    }
}

// ---------------- per-mode 64x64 complex multiply (unchanged) ---------------------
__global__ __launch_bounds__(256) void specmul_kernel(
    const float2* __restrict__ fm,
    const float* __restrict__ w1r, const float* __restrict__ w1i,
    const float* __restrict__ w2r, const float* __restrict__ w2i,
    float2* __restrict__ fm2, int nb64)
{
    __shared__ float2 lx[32 * 64];
    __shared__ float2 lw[64 * 64];
    int t = threadIdx.x;
    int mode = blockIdx.x;
    int region = mode / 400;
    int km = mode % 400;
    int kyi = region * 20 + (km / 20);
    int kx = km % 20;
    const float* wr = region ? w2r : w1r;
    const float* wi = region ? w2i : w1i;
    int modeoff = kyi * 20 + kx;
    for (int n = t; n < nb64; n += 256)
        lx[n] = fm[(size_t)n * 800 + modeoff];
    for (int n = t; n < 4096; n += 256) {
        size_t a = (size_t)n * 400 + km;
        lw[n] = make_float2(wr[a], wi[a]);
    }
    __syncthreads();
    for (int n = t; n < nb64; n += 256) {
        int b = n >> 6, o = n & 63;
        float re = 0.f, imv = 0.f;
        const float2* xb = lx + b * 64;
#pragma unroll 8
        for (int i = 0; i < 64; ++i) {
            float2 a = xb[i];
            float2 w = lw[i * 64 + o];
            re += a.x * w.x - a.y * w.y;
            imv += a.x * w.y + a.y * w.x;
        }
        fm2[(size_t)n * 800 + modeoff] = make_float2(re, imv);
    }
}

// ---------------- invA (MFMA): fm2 [bc][800] -> g bf16 [bc][y][48] -----------------
__global__ __launch_bounds__(256) void invA_mfma_kernel(
    const float2* __restrict__ fm2, const short* __restrict__ Tiy,
    short* __restrict__ g)
{
    __shared__ short F[48 * 104];    // [n][q] pad104
    int t = threadIdx.x;
    int bc = blockIdx.x;
    int lane = t & 63, w = t >> 6;
    u32* Fw = (u32*)F;
    const float2* src = fm2 + (size_t)bc * 800;
    for (int i = t; i < 800; i += 256) {
        float2 v = src[i];
        int kyi = i / 20, kx = i - kyi * 20;
        Fw[(2 * kx) * 52 + kyi]     = pack2(v.x, -v.y);
        Fw[(2 * kx + 1) * 52 + kyi] = pack2(v.y, v.x);
    }
    for (int i = t; i < 416; i += 256) Fw[2080 + i] = 0u;           // rows 40..47
    for (int i = t; i < 384; i += 256) {                             // cols 80..95
        int n = i >> 3, k = i & 7;
        Fw[n * 52 + 40 + k] = 0u;
    }
    __syncthreads();

    short8 aF[3][3];
#pragma unroll
    for (int mt = 0; mt < 3; ++mt)
#pragma unroll
        for (int ks = 0; ks < 3; ++ks)
            aF[mt][ks] = *(const short8*)&F[(mt * 16 + (lane & 15)) * 104 + ks * 32 + (lane >> 4) * 8];

#pragma unroll
    for (int ni = 0; ni < 2; ++ni) {
        int nt = w * 2 + ni;
        int yy = nt * 16 + (lane & 15);
        short8 bF[3];
#pragma unroll
        for (int ks = 0; ks < 3; ++ks)
            bF[ks] = *(const short8*)(Tiy + yy * 96 + ks * 32 + (lane >> 4) * 8);
#pragma unroll
        for (int mt = 0; mt < 3; ++mt) {
            f32x4 acc = (f32x4){0.f, 0.f, 0.f, 0.f};
#pragma unroll
            for (int ks = 0; ks < 3; ++ks)
                acc = __builtin_amdgcn_mfma_f32_16x16x32_bf16(aF[mt][ks], bF[ks], acc, 0, 0, 0);
            int n0 = mt * 16 + (lane >> 4) * 4;
            *(int2*)&g[((size_t)bc * 128 + yy) * 48 + n0] =
                make_int2(pack2(acc[0], acc[1]), pack2(acc[2], acc[3]));
        }
    }
}

// ---------------- invB (MFMA): per (b, 4-y tile) -> s1g bf16 [b][y][x][c] ----------
__global__ __launch_bounds__(256) void invB_mfma_kernel(
    const short* __restrict__ g, const short* __restrict__ Winvbg,
    short* __restrict__ s1g)
{
    __shared__ short A[4 * 64 * 64];
    int t = threadIdx.x;
    int tile = blockIdx.x;
    int b = blockIdx.y;
    int lane = t & 63, w = t >> 6;
    int y0 = tile * 4;

    short8 bF[8][2];
#pragma unroll
    for (int nf = 0; nf < 8; ++nf)
#pragma unroll
        for (int ks = 0; ks < 2; ++ks) {
            int xx = nf * 16 + (lane & 15);
            bF[nf][ks] = *(const short8*)(Winvbg + xx * 64 + ks * 32 + (lane >> 4) * 8);
        }

    const short* gb = g + (size_t)b * 64 * 128 * 48;
    short8 vz = {0, 0, 0, 0, 0, 0, 0, 0};
#pragma unroll
    for (int i = 0; i < 8; ++i) {
        int chunk = i * 256 + t;
        int y = chunk >> 9, c = (chunk >> 3) & 63, g8 = chunk & 7;
        short8 v = (g8 < 6) ? *(const short8*)(gb + ((size_t)c * 128 + y0 + y) * 48 + g8 * 8) : vz;
        *(short8*)&A[((y * 64 + c) << 6) + ((g8 ^ (c & 7)) << 3)] = v;
    }
    __syncthreads();

    int c0 = w * 16;
#pragma unroll
    for (int y = 0; y < 4; ++y) {
        int c = c0 + (lane & 15);
        int base = (y * 64 + c) << 6;
        short8 aF0 = *(const short8*)&A[base + (((lane >> 4) ^ (c & 7)) << 3)];
        short8 aF1 = *(const short8*)&A[base + (((4 + (lane >> 4)) ^ (c & 7)) << 3)];
        short* orow = s1g + ((size_t)(b * 128 + y0 + y)) * 128 * 64;
#pragma unroll
        for (int nf = 0; nf < 8; ++nf) {
            f32x4 acc = (f32x4){0.f, 0.f, 0.f, 0.f};
            acc = __builtin_amdgcn_mfma_f32_16x16x32_bf16(aF0, bF[nf][0], acc, 0, 0, 0);
            acc = __builtin_amdgcn_mfma_f32_16x16x32_bf16(aF1, bF[nf][1], acc, 0, 0, 0);
            int xx = nf * 16 + (lane & 15);
            int cw = c0 + (lane >> 4) * 4;
            *(int2*)&orow[xx * 64 + cw] = make_int2(pack2(acc[0], acc[1]), pack2(acc[2], acc[3]));
        }
    }
}

// ---------------- conv 3x3 (MFMA), reads xb16 c-last -> c2g bf16 [b][y][x][c] -----
__global__ __launch_bounds__(256) void conv3_mfma_kernel(
    const short* __restrict__ xb16,
    const short* __restrict__ wpk,
    const float* __restrict__ cb,
    short* __restrict__ c2g)
{
    __shared__ short xlds[3 * 128 * 64];
    int t = threadIdx.x;
    int y = blockIdx.x;
    int b = blockIdx.y;
    int lane = t & 63, wid = t >> 6;

    const short8* xs = (const short8*)(xb16 + ((size_t)b * 128) * 128 * 64);
#pragma unroll
    for (int i = 0; i < 12; ++i) {
        int c = i * 256 + t;           // 3072 chunks
        int row = c >> 10;
        int rem = c & 1023;
        int xx = rem >> 3, i8 = rem & 7;
        int yy = (y + row + 127) & 127;
        short8 v = xs[((size_t)yy * 128 + xx) * 8 + i8];
        *(short8*)&xlds[(row * 128 + xx) * 64 + ((i8 ^ (xx & 7)) << 3)] = v;
    }

    int o0 = wid * 16;
    const short* wbase = wpk + (size_t)(o0 + (lane & 15)) * 576 + (lane >> 4) * 8;
    short8 aF[18];
#pragma unroll
    for (int s = 0; s < 18; ++s)
        aF[s] = *(const short8*)(wbase + s * 32);

    __syncthreads();

    f32x4 acc[8];
#pragma unroll
    for (int f = 0; f < 8; ++f) acc[f] = (f32x4){0.f, 0.f, 0.f, 0.f};
#pragma unroll
    for (int s = 0; s < 18; ++s) {
        const int tap = s >> 1;
        const int ky = tap / 3, kx = tap % 3;
        int ig = (s & 1) * 4 + (lane >> 4);
#pragma unroll
        for (int f = 0; f < 8; ++f) {
            int xx = (f * 16 + (lane & 15) + kx + 127) & 127;
            int off = (ky * 128 + xx) * 64 + ((ig ^ (xx & 7)) << 3);
            short8 bG = *(const short8*)&xlds[off];
            acc[f] = __builtin_amdgcn_mfma_f32_16x16x32_bf16(aF[s], bG, acc[f], 0, 0, 0);
        }
    }

    int ob = o0 + (lane >> 4) * 4;
    float bias0 = cb[ob], bias1 = cb[ob + 1], bias2 = cb[ob + 2], bias3 = cb[ob + 3];
    short* orow = c2g + ((size_t)(b * 128 + y)) * 128 * 64;
#pragma unroll
    for (int f = 0; f < 8; ++f) {
        int x = f * 16 + (lane & 15);
        *(int2*)&orow[x * 64 + ob] = make_int2(pack2(acc[f][0] + bias0, acc[f][1] + bias1),
                                               pack2(acc[f][2] + bias2, acc[f][3] + bias3));
    }
}

// ---------------- combine (MFMA): in-place residual + writes xb16 -----------------
__global__ __launch_bounds__(256) void combine_mfma_kernel(
    const short* __restrict__ s1g,
    const short* __restrict__ c2g,
    const short* __restrict__ pwk,
    const float* __restrict__ pw,
    const float* __restrict__ pb,
    float* __restrict__ xio,
    short* __restrict__ xb16)
{
    __shared__ short S1[128 * 64];
    __shared__ short C2[128 * 64];
    __shared__ float2 pr[128];
    int t = threadIdx.x;
    int y = blockIdx.x;
    int b = blockIdx.y;
    int lane = t & 63, w = t >> 6;

    const short* s1b = s1g + ((size_t)(b * 128 + y)) * 128 * 64;
    const short* c2b = c2g + ((size_t)(b * 128 + y)) * 128 * 64;
#pragma unroll
    for (int i = 0; i < 4; ++i) {
        int chunk = i * 256 + t;
        int xx = chunk >> 3, c8 = chunk & 7;
        int dst = xx * 64 + ((c8 ^ (xx & 7)) << 3);
        *(short8*)&S1[dst] = *(const short8*)(s1b + chunk * 8);
        *(short8*)&C2[dst] = *(const short8*)(c2b + chunk * 8);
    }
    if (t < 128) {
        const short* sp = s1b + t * 64;
        float v0 = __builtin_bit_cast(float, (u32)(unsigned short)sp[0] << 16);
        float v1 = __builtin_bit_cast(float, (u32)(unsigned short)sp[1] << 16);
        float v2 = __builtin_bit_cast(float, (u32)(unsigned short)sp[2] << 16);
        float v3 = __builtin_bit_cast(float, (u32)(unsigned short)sp[3] << 16);
        pr[t] = make_float2(v0 * v2, v1 * v3);
    }

    short8 bF[4][4];
#pragma unroll
    for (int nf = 0; nf < 4; ++nf)
#pragma unroll
        for (int ks = 0; ks < 4; ++ks) {
            int o = nf * 16 + (lane & 15);
            bF[nf][ks] = *(const short8*)(pwk + o * 128 + ks * 32 + (lane >> 4) * 8);
        }
    __syncthreads();

    f32x4 acc[2][4];
#pragma unroll
    for (int a = 0; a < 2; ++a)
#pragma unroll
        for (int b2 = 0; b2 < 4; ++b2) acc[a][b2] = (f32x4){0.f, 0.f, 0.f, 0.f};

#pragma unroll
    for (int ks = 0; ks < 4; ++ks)
#pragma unroll
        for (int mf = 0; mf < 2; ++mf) {
            int xx = w * 32 + mf * 16 + (lane & 15);
            int k0 = ks * 32 + (lane >> 4) * 8;
            const short* src = (ks < 2) ? &S1[xx * 64 + ((((k0 >> 3) ^ (xx & 7))) << 3)]
                                        : &C2[xx * 64 + (((((k0 - 64) >> 3) ^ (xx & 7))) << 3)];
            short8 aF = *(const short8*)src;
#pragma unroll
            for (int nf = 0; nf < 4; ++nf)
                acc[mf][nf] = __builtin_amdgcn_mfma_f32_16x16x32_bf16(aF, bF[nf][ks], acc[mf][nf], 0, 0, 0);
        }

#pragma unroll
    for (int mf = 0; mf < 2; ++mf) {
        int xr = w * 32 + mf * 16 + (lane >> 4) * 4;
        float2 prv0 = pr[xr], prv1 = pr[xr + 1], prv2 = pr[xr + 2], prv3 = pr[xr + 3];
#pragma unroll
        for (int nf = 0; nf < 4; ++nf) {
            int o = nf * 16 + (lane & 15);
            const float* pwrow = pw + o * 130;
            float pw128 = pwrow[128], pw129 = pwrow[129], pbv = pb[o];
            size_t off = ((size_t)(b * 64 + o)) * HW + y * 128 + xr;
            f32x4 xov = *(const f32x4*)(xio + off);
            f32x4 res;
            res[0] = xov[0] + tanhf(acc[mf][nf][0] + pbv + pw128 * prv0.x + pw129 * prv0.y);
            res[1] = xov[1] + tanhf(acc[mf][nf][1] + pbv + pw128 * prv1.x + pw129 * prv1.y);
            res[2] = xov[2] + tanhf(acc[mf][nf][2] + pbv + pw128 * prv2.x + pw129 * prv2.y);
            res[3] = xov[3] + tanhf(acc[mf][nf][3] + pbv + pw128 * prv3.x + pw129 * prv3.y);
            *(f32x4*)(xio + off) = res;
            size_t hbase = (((size_t)(b * 128 + y)) * 128 + xr) * 64 + o;
            xb16[hbase]           = (short)f2bf(res[0]);
            xb16[hbase + 64]      = (short)f2bf(res[1]);
            xb16[hbase + 128]     = (short)f2bf(res[2]);
            xb16[hbase + 192]     = (short)f2bf(res[3]);
        }
    }
}

// ---------------- fc1 (MFMA): xb16 -> gelu MLP -> out ------------------------------
__global__ __launch_bounds__(256) void fc1_mfma_kernel(
    const short* __restrict__ xb16,
    const short* __restrict__ f1wk, const float* __restrict__ b1,
    const float* __restrict__ w2, const float* __restrict__ b2,
    float* __restrict__ out)
{
    __shared__ short X[128 * 72];
    __shared__ float lb1[128], lw2[128];
    int t = threadIdx.x;
    int y = blockIdx.x, b = blockIdx.y;
    int lane = t & 63, w = t >> 6;
    if (t < 128) { lb1[t] = b1[t]; lw2[t] = w2[t]; }
    const short8* src = (const short8*)(xb16 + (((size_t)b * 128 + y) * 128) * 64);
#pragma unroll
    for (int i = 0; i < 4; ++i) {
        int c = i * 256 + t;
        int xx = c >> 3, c8 = c & 7;
        *(short8*)&X[xx * 72 + ((c8 ^ (xx & 7)) << 3)] = src[c];
    }
    __syncthreads();

    float part0 = 0.f, part1 = 0.f;
#pragma unroll
    for (int mt = 0; mt < 8; ++mt) {
        short8 aF[2];
#pragma unroll
        for (int ks = 0; ks < 2; ++ks)
            aF[ks] = *(const short8*)(f1wk + (mt * 16 + (lane & 15)) * 64 + ks * 32 + (lane >> 4) * 8);
#pragma unroll
        for (int ni = 0; ni < 2; ++ni) {
            int xx = (w * 2 + ni) * 16 + (lane & 15);
            f32x4 acc = (f32x4){0.f, 0.f, 0.f, 0.f};
#pragma unroll
            for (int ks = 0; ks < 2; ++ks) {
                int g8 = ks * 4 + (lane >> 4);
                short8 bF = *(const short8*)&X[xx * 72 + ((g8 ^ (xx & 7)) << 3)];
                acc = __builtin_amdgcn_mfma_f32_16x16x32_bf16(aF[ks], bF, acc, 0, 0, 0);
            }
            int m0 = mt * 16 + (lane >> 4) * 4;
            float s = lw2[m0]     * gelu_tanh(acc[0] + lb1[m0])
                    + lw2[m0 + 1] * gelu_tanh(acc[1] + lb1[m0 + 1])
                    + lw2[m0 + 2] * gelu_tanh(acc[2] + lb1[m0 + 2])
                    + lw2[m0 + 3] * gelu_tanh(acc[3] + lb1[m0 + 3]);
            if (ni == 0) part0 += s; else part1 += s;
        }
    }
    part0 += __shfl_xor(part0, 16); part0 += __shfl_xor(part0, 32);
    part1 += __shfl_xor(part1, 16); part1 += __shfl_xor(part1, 32);
    if (lane < 16) {
        float bb = b2[0];
        out[(size_t)b * HW + y * 128 + (w * 2) * 16 + lane] = part0 + bb;
        out[(size_t)b * HW + y * 128 + (w * 2 + 1) * 16 + lane] = part1 + bb;
    }
}

extern "C" void kernel_launch(void* const* d_in, const int* in_sizes, int n_in,
                              void* d_out, int out_size, void* d_ws, size_t ws_size,
                              hipStream_t stream) {
    const float* x      = (const float*)d_in[0];
    const float* qa     = (const float*)d_in[1];
    const float* qb     = (const float*)d_in[2];
    const float* fc0w1  = (const float*)d_in[3];
    const float* fc0b1  = (const float*)d_in[4];
    const float* fc0w2  = (const float*)d_in[5];
    const float* fc0b2  = (const float*)d_in[6];
    const float* sw1r   = (const float*)d_in[7];
    const float* sw1i   = (const float*)d_in[8];
    const float* sw2r   = (const float*)d_in[9];
    const float* sw2i   = (const float*)d_in[10];
    const float* cw     = (const float*)d_in[11];
    const float* cb     = (const float*)d_in[12];
    const float* pw     = (const float*)d_in[13];
    const float* pb     = (const float*)d_in[14];
    const float* fc1w1  = (const float*)d_in[15];
    const float* fc1b1  = (const float*)d_in[16];
    const float* fc1w2  = (const float*)d_in[17];
    const float* fc1b2  = (const float*)d_in[18];

    // const packs (floats)
    const size_t WPK_F = 73728, PWK_F = 16384, WFG_F = 3072, WIB_F = 4096;
    const size_t TFY_F = 5120, TIY_F = 6144, FCK_F = 9216;
    const size_t CONST_F = WPK_F + PWK_F + WFG_F + WIB_F + TFY_F + TIY_F + FCK_F;
    // per-batch floats: xA 1048576 + xb16 524288 + s1g 524288 + c2g 524288
    //                 + out1g 163840 + g 196608 + fm 102400 + fm2 102400
    const size_t PER_B_F = 1048576u + 3u * 524288u + 163840u + 196608u + 2u * 102400u;
    int NB = 32;
    while (NB > 1 && ((size_t)NB * PER_B_F + CONST_F) * 4 > ws_size) NB >>= 1;
    if (((size_t)NB * PER_B_F + CONST_F) * 4 > ws_size) return;

    float* fb = (float*)d_ws;
    short* wpk    = (short*)fb;                 fb += WPK_F;
    short* pwk    = (short*)fb;                 fb += PWK_F;
    short* Wfg    = (short*)fb;                 fb += WFG_F;
    short* Winvbg = (short*)fb;                 fb += WIB_F;
    short* Tfy    = (short*)fb;                 fb += TFY_F;
    short* Tiy    = (short*)fb;                 fb += TIY_F;
    short* w1k    = (short*)fb;
    short* w2k    = w1k + 4096;
    short* f1wk   = w1k + 10240;                fb += FCK_F;

    float*  xA    = fb;
    short*  xb16  = (short*)(xA + (size_t)NB * 1048576u);
    short*  s1g   = xb16 + (size_t)NB * 1048576u;
    short*  c2g   = s1g + (size_t)NB * 1048576u;
    short*  out1g = c2g + (size_t)NB * 1048576u;
    short*  g     = out1g + (size_t)NB * 327680u;
    float2* fm    = (float2*)(g + (size_t)NB * 393216u);
    float2* fm2   = fm + (size_t)NB * 51200u;

    packw_kernel<<<576, 256, 0, stream>>>(cw, wpk);
    packpw_kernel<<<128, 256, 0, stream>>>(pw, pwk);
    packfc_kernel<<<72, 256, 0, stream>>>(fc0w1, fc0w2, fc1w1, w1k, w2k, f1wk);
    gen_dft_kernel<<<144, 256, 0, stream>>>(Wfg, Winvbg, Tfy, Tiy);

    for (int b0 = 0; b0 < 32; b0 += NB) {
        front_mfma_kernel<<<dim3(128, NB), 256, 0, stream>>>(
            x + (size_t)b0 * 10 * HW, qa, qb, w1k, fc0b1, w2k, fc0b2, xA, xb16);

        for (int L = 0; L < 4; ++L) {
            const size_t swoff = (size_t)L * 1638400;
            dft1_mfma_kernel<<<NB * 64, 256, 0, stream>>>(xA, Wfg, out1g);
            dft2_mfma_kernel<<<NB * 64, 256, 0, stream>>>(out1g, Tfy, fm);
            specmul_kernel<<<800, 256, 0, stream>>>(fm, sw1r + swoff, sw1i + swoff,
                                                    sw2r + swoff, sw2i + swoff, fm2, NB * 64);
            invA_mfma_kernel<<<NB * 64, 256, 0, stream>>>(fm2, Tiy, g);
            invB_mfma_kernel<<<dim3(32, NB), 256, 0, stream>>>(g, Winvbg, s1g);
            conv3_mfma_kernel<<<dim3(128, NB), 256, 0, stream>>>(
                xb16, wpk + (size_t)L * 36864, cb + (size_t)L * 64, c2g);
            combine_mfma_kernel<<<dim3(128, NB), 256, 0, stream>>>(
                s1g, c2g, pwk + (size_t)L * 8192, pw + (size_t)L * 8320,
                pb + (size_t)L * 64, xA, xb16);
        }

        fc1_mfma_kernel<<<dim3(128, NB), 256, 0, stream>>>(
            xb16, f1wk, fc1b1, fc1w2, fc1b2, (float*)d_out + (size_t)b0 * HW);
    }
}